// Round 1
// baseline (272.456 us; speedup 1.0000x reference)
//
#include <hip/hip_runtime.h>
#include <hip/hip_bf16.h>

typedef __hip_bfloat16 bf16;
typedef __attribute__((ext_vector_type(8))) short short8;
typedef __attribute__((ext_vector_type(4))) float f32x4;

#define B_SZ 32
#define N_SZ 512
#define L_SZ 1024
#define D_SZ 512
#define H_SZ 8

__device__ __forceinline__ void gload16(void* lds, const void* g) {
    typedef const __attribute__((address_space(1))) unsigned int* gp_t;
    typedef __attribute__((address_space(3))) unsigned int* lp_t;
    __builtin_amdgcn_global_load_lds((gp_t)g, (lp_t)lds, 16, 0, 0);
}

// ---------------- f32 -> bf16 convert (vectorized) ----------------
struct alignas(8) B4 { bf16 a, b, c, d; };

__global__ void cvt4(const float* __restrict__ s, bf16* __restrict__ d, int n4) {
    int i = blockIdx.x * 256 + threadIdx.x;
    if (i < n4) {
        float4 v = ((const float4*)s)[i];
        B4 o;
        o.a = __float2bfloat16(v.x);
        o.b = __float2bfloat16(v.y);
        o.c = __float2bfloat16(v.z);
        o.d = __float2bfloat16(v.w);
        *(B4*)(d + (size_t)i * 4) = o;
    }
}

// ---------------- 512x512 transpose + convert: Wt[e][d] = bf16(W[d][e]) ----------------
__global__ void tpose4(const float* __restrict__ s0, const float* __restrict__ s1,
                       const float* __restrict__ s2, const float* __restrict__ s3,
                       bf16* __restrict__ d0, bf16* __restrict__ d1,
                       bf16* __restrict__ d2, bf16* __restrict__ d3) {
    __shared__ float t[32][33];
    const float* s = blockIdx.z == 0 ? s0 : blockIdx.z == 1 ? s1 : blockIdx.z == 2 ? s2 : s3;
    bf16* d = blockIdx.z == 0 ? d0 : blockIdx.z == 1 ? d1 : blockIdx.z == 2 ? d2 : d3;
    int tx = threadIdx.x, ty = threadIdx.y;  // 32 x 8
    int r0 = blockIdx.y * 32, c0 = blockIdx.x * 32;
#pragma unroll
    for (int i = 0; i < 32; i += 8)
        t[ty + i][tx] = s[(size_t)(r0 + ty + i) * 512 + c0 + tx];
    __syncthreads();
#pragma unroll
    for (int i = 0; i < 32; i += 8)
        d[(size_t)(c0 + ty + i) * 512 + r0 + tx] = __float2bfloat16(t[tx][ty + i]);
}

// ---------------- GEMM: C[M x 512] = A[M x 512] * W, A bf16, Wt[e][d] bf16 ----------------
// MODE 0: Q  -> bf16 head-split [b][h][s][c]          (S = 512)
// MODE 1: K  -> bf16 head-split [b][h][s][c] + rpb    (S = 1024)
// MODE 2: V  -> bf16 transposed [b][h][c][l]          (S = 1024)
// MODE 3: O  -> f32 row-major [m][e] + bo
template <int MODE>
__global__ __launch_bounds__(256) void gemm512(const bf16* __restrict__ A,
                                               const bf16* __restrict__ Bt,
                                               void* __restrict__ outp,
                                               const float* __restrict__ bias, int logS) {
    __shared__ bf16 lA[128 * 32];
    __shared__ bf16 lB[128 * 32];
    const int tid = threadIdx.x;
    const int wave = tid >> 6, lane = tid & 63;
    const int wr = wave >> 1, wc = wave & 1;
    const int g16 = lane >> 4, r16 = lane & 15;
    const long rowBase = (long)blockIdx.x * 128;
    const int colBase = blockIdx.y * 128;

    f32x4 acc[4][4];
#pragma unroll
    for (int m = 0; m < 4; ++m)
#pragma unroll
        for (int n = 0; n < 4; ++n) acc[m][n] = {0.f, 0.f, 0.f, 0.f};

    for (int k0 = 0; k0 < 512; k0 += 32) {
        __syncthreads();
#pragma unroll
        for (int half = 0; half < 2; ++half) {
            int cbase = half * 256 + wave * 64;
            int chunk = cbase + lane;
            int row = chunk >> 2;
            int kc = (chunk & 3) ^ (row & 3);  // swizzled global source, linear LDS dest
            gload16((char*)lA + cbase * 16, A + (rowBase + row) * 512 + k0 + kc * 8);
            gload16((char*)lB + cbase * 16, Bt + (long)(colBase + row) * 512 + k0 + kc * 8);
        }
        __syncthreads();
        short8 a[4], b[4];
#pragma unroll
        for (int m = 0; m < 4; ++m) {
            int row = wr * 64 + m * 16 + r16;
            a[m] = *(const short8*)((const char*)lA + row * 64 + ((g16 ^ (row & 3)) * 16));
        }
#pragma unroll
        for (int n = 0; n < 4; ++n) {
            int row = wc * 64 + n * 16 + r16;
            b[n] = *(const short8*)((const char*)lB + row * 64 + ((g16 ^ (row & 3)) * 16));
        }
#pragma unroll
        for (int m = 0; m < 4; ++m)
#pragma unroll
            for (int n = 0; n < 4; ++n)
                acc[m][n] = __builtin_amdgcn_mfma_f32_16x16x32_bf16(a[m], b[n], acc[m][n], 0, 0, 0);
    }

    const int S = 1 << logS;
#pragma unroll
    for (int m = 0; m < 4; ++m) {
#pragma unroll
        for (int r = 0; r < 4; ++r) {
            long gm = rowBase + wr * 64 + m * 16 + g16 * 4 + r;
            int bb = (int)(gm >> logS);
            int s = (int)gm & (S - 1);
#pragma unroll
            for (int n = 0; n < 4; ++n) {
                int e = colBase + wc * 64 + n * 16 + r16;
                float v = acc[m][n][r];
                if (MODE == 1) v += bias[(long)s * 512 + e];
                if (MODE == 3) {
                    ((float*)outp)[gm * 512 + e] = v + bias[e];
                } else {
                    int h = e >> 6, c = e & 63;
                    long idx;
                    if (MODE == 2)
                        idx = (((long)bb * H_SZ + h) * 64 + c) * (long)L_SZ + s;
                    else
                        idx = (((long)bb * H_SZ + h) * (long)S + s) * 64 + c;
                    ((bf16*)outp)[idx] = __float2bfloat16(v);
                }
            }
        }
    }
}

// ---------------- flash attention: 1 block = (qblock of 64, b*h) ----------------
__global__ __launch_bounds__(256) void attn64(const bf16* __restrict__ q,
                                              const bf16* __restrict__ k,
                                              const bf16* __restrict__ vT,
                                              const int* __restrict__ mask,
                                              bf16* __restrict__ o) {
    __shared__ bf16 lQ[64 * 64];
    __shared__ bf16 lK[64 * 64];
    __shared__ bf16 lV[64 * 64];  // [c][l]
    __shared__ bf16 lP[4][16 * 64];
    __shared__ int lM[64];

    const int tid = threadIdx.x;
    const int wave = tid >> 6, lane = tid & 63;
    const int g16 = lane >> 4, r16 = lane & 15;
    const int bh = blockIdx.y;
    const int b = bh >> 3, h = bh & 7;
    const long qoff = ((long)bh * N_SZ + blockIdx.x * 64) * 64;
    const long koff = (long)bh * L_SZ * 64;
    const long voff = (long)bh * 64 * L_SZ;

    // stage Q tile (contiguous 8KB), swizzled source
#pragma unroll
    for (int half = 0; half < 2; ++half) {
        int cbase = half * 256 + wave * 64;
        int chunk = cbase + lane;
        int row = chunk >> 3;
        int lc = (chunk & 7) ^ (row & 7);
        gload16((char*)lQ + cbase * 16, q + qoff + row * 64 + lc * 8);
    }

    float mrun[4] = {-3.0e38f, -3.0e38f, -3.0e38f, -3.0e38f};
    float lrun[4] = {0.f, 0.f, 0.f, 0.f};
    f32x4 oacc[4];
#pragma unroll
    for (int cb = 0; cb < 4; ++cb) oacc[cb] = {0.f, 0.f, 0.f, 0.f};

    for (int kb = 0; kb < 16; ++kb) {
        __syncthreads();
        const bf16* kg = k + koff + kb * 64 * 64;
        const bf16* vg = vT + voff + kb * 64;
#pragma unroll
        for (int half = 0; half < 2; ++half) {
            int cbase = half * 256 + wave * 64;
            int chunk = cbase + lane;
            int row = chunk >> 3;
            int lc = (chunk & 7) ^ (row & 7);
            gload16((char*)lK + cbase * 16, kg + row * 64 + lc * 8);
            gload16((char*)lV + cbase * 16, vg + (long)row * L_SZ + lc * 8);
        }
        if (tid < 64) lM[tid] = mask[b * L_SZ + kb * 64 + tid];
        __syncthreads();

        // S = Q K^T  (rows q: g16*4+r, cols l: n*16+r16)
        short8 aq0 = *(const short8*)((const char*)lQ + (wave * 16 + r16) * 128 +
                                      ((0 + g16) ^ (r16 & 7)) * 16);
        short8 aq1 = *(const short8*)((const char*)lQ + (wave * 16 + r16) * 128 +
                                      ((4 + g16) ^ (r16 & 7)) * 16);
        f32x4 s[4];
#pragma unroll
        for (int n = 0; n < 4; ++n) {
            int row = n * 16 + r16;
            short8 bk0 = *(const short8*)((const char*)lK + row * 128 + ((0 + g16) ^ (r16 & 7)) * 16);
            short8 bk1 = *(const short8*)((const char*)lK + row * 128 + ((4 + g16) ^ (r16 & 7)) * 16);
            f32x4 z = {0.f, 0.f, 0.f, 0.f};
            z = __builtin_amdgcn_mfma_f32_16x16x32_bf16(aq0, bk0, z, 0, 0, 0);
            z = __builtin_amdgcn_mfma_f32_16x16x32_bf16(aq1, bk1, z, 0, 0, 0);
            s[n] = z;
        }
        // scale + pad mask (mask true -> -FLT_MAX)
#pragma unroll
        for (int n = 0; n < 4; ++n) {
            bool msk = lM[n * 16 + r16] != 0;
#pragma unroll
            for (int r = 0; r < 4; ++r) s[n][r] = msk ? -3.0e38f : s[n][r] * 0.125f;
        }
        // online softmax, per output row (g16*4 + r)
        float alpha[4];
#pragma unroll
        for (int r = 0; r < 4; ++r) {
            float tmax = fmaxf(fmaxf(s[0][r], s[1][r]), fmaxf(s[2][r], s[3][r]));
            tmax = fmaxf(tmax, __shfl_xor(tmax, 1));
            tmax = fmaxf(tmax, __shfl_xor(tmax, 2));
            tmax = fmaxf(tmax, __shfl_xor(tmax, 4));
            tmax = fmaxf(tmax, __shfl_xor(tmax, 8));
            float mnew = fmaxf(mrun[r], tmax);
            float a_ = __expf(mrun[r] - mnew);
            mrun[r] = mnew;
            float psum = 0.f;
#pragma unroll
            for (int n = 0; n < 4; ++n) {
                float p = __expf(s[n][r] - mnew);
                s[n][r] = p;
                psum += p;
            }
            psum += __shfl_xor(psum, 1);
            psum += __shfl_xor(psum, 2);
            psum += __shfl_xor(psum, 4);
            psum += __shfl_xor(psum, 8);
            lrun[r] = lrun[r] * a_ + psum;
            alpha[r] = a_;
        }
#pragma unroll
        for (int cb = 0; cb < 4; ++cb)
#pragma unroll
            for (int r = 0; r < 4; ++r) oacc[cb][r] = oacc[cb][r] * alpha[r];

        // P -> LDS (per-wave, swizzled), then PV
        bf16* Pw = lP[wave];
#pragma unroll
        for (int n = 0; n < 4; ++n) {
#pragma unroll
            for (int r = 0; r < 4; ++r) {
                int row = g16 * 4 + r;
                int col = n * 16 + r16;
                int cs = (col >> 3) ^ (row & 7);
                *((bf16*)((char*)Pw + row * 128 + cs * 16 + (col & 7) * 2)) =
                    __float2bfloat16(s[n][r]);
            }
        }
        short8 ap0 = *(const short8*)((const char*)Pw + r16 * 128 + ((0 + g16) ^ (r16 & 7)) * 16);
        short8 ap1 = *(const short8*)((const char*)Pw + r16 * 128 + ((4 + g16) ^ (r16 & 7)) * 16);
#pragma unroll
        for (int cb = 0; cb < 4; ++cb) {
            int row = cb * 16 + r16;
            short8 bv0 = *(const short8*)((const char*)lV + row * 128 + ((0 + g16) ^ (r16 & 7)) * 16);
            short8 bv1 = *(const short8*)((const char*)lV + row * 128 + ((4 + g16) ^ (r16 & 7)) * 16);
            oacc[cb] = __builtin_amdgcn_mfma_f32_16x16x32_bf16(ap0, bv0, oacc[cb], 0, 0, 0);
            oacc[cb] = __builtin_amdgcn_mfma_f32_16x16x32_bf16(ap1, bv1, oacc[cb], 0, 0, 0);
        }
    }

    // epilogue: o[b][qg][h*64 + c] bf16
#pragma unroll
    for (int r = 0; r < 4; ++r) {
        float inv = 1.0f / lrun[r];
        int qg = blockIdx.x * 64 + wave * 16 + g16 * 4 + r;
#pragma unroll
        for (int cb = 0; cb < 4; ++cb) {
            int c = cb * 16 + r16;
            o[((long)b * N_SZ + qg) * 512 + h * 64 + c] = __float2bfloat16(oacc[cb][r] * inv);
        }
    }
}

extern "C" void kernel_launch(void* const* d_in, const int* in_sizes, int n_in,
                              void* d_out, int out_size, void* d_ws, size_t ws_size,
                              hipStream_t stream) {
    const float* x_q  = (const float*)d_in[0];
    const float* x_kv = (const float*)d_in[1];
    const int*   mask = (const int*)d_in[2];
    const float* Wq   = (const float*)d_in[3];
    const float* Wk   = (const float*)d_in[4];
    const float* Wv   = (const float*)d_in[5];
    const float* Wo   = (const float*)d_in[6];
    const float* bo   = (const float*)d_in[7];
    const float* rpb  = (const float*)d_in[8];
    float* out = (float*)d_out;

    char* w = (char*)d_ws;
    bf16* xq_bf  = (bf16*)(w + 0);           // 16.78 MB; reused as o_bf after attention
    bf16* xkv_bf = (bf16*)(w + 16777216);    // 33.55 MB
    bf16* WqT    = (bf16*)(w + 50331648);    // 4 x 0.52 MB
    bf16* WkT    = WqT + 262144;
    bf16* WvT    = WkT + 262144;
    bf16* WoT    = WvT + 262144;
    bf16* qh     = (bf16*)(w + 52428800);    // 16.78 MB  [b][h][n][c]
    bf16* kh     = (bf16*)(w + 69206016);    // 33.55 MB  [b][h][l][c]
    bf16* vTh    = (bf16*)(w + 102760448);   // 33.55 MB  [b][h][c][l]
    bf16* o_bf   = xq_bf;

    cvt4<<<8192, 256, 0, stream>>>(x_q, xq_bf, 2097152);
    cvt4<<<16384, 256, 0, stream>>>(x_kv, xkv_bf, 4194304);
    tpose4<<<dim3(16, 16, 4), dim3(32, 8), 0, stream>>>(Wq, Wk, Wv, Wo, WqT, WkT, WvT, WoT);

    gemm512<0><<<dim3(128, 4), 256, 0, stream>>>(xq_bf, WqT, qh, nullptr, 9);
    gemm512<1><<<dim3(256, 4), 256, 0, stream>>>(xkv_bf, WkT, kh, rpb, 10);
    gemm512<2><<<dim3(256, 4), 256, 0, stream>>>(xkv_bf, WvT, vTh, nullptr, 10);

    attn64<<<dim3(8, 256), 256, 0, stream>>>(qh, kh, vTh, mask, o_bf);

    gemm512<3><<<dim3(128, 4), 256, 0, stream>>>(o_bf, WoT, out, bo, 9);
}

// Round 3
// 219.137 us; speedup vs baseline: 1.2433x; 1.2433x over previous
//
#include <hip/hip_runtime.h>
#include <hip/hip_bf16.h>

typedef __hip_bfloat16 bf16;
typedef __attribute__((ext_vector_type(8))) short short8;
typedef __attribute__((ext_vector_type(4))) float f32x4;
typedef __attribute__((ext_vector_type(16))) float f32x16;

#define B_SZ 32
#define N_SZ 512
#define L_SZ 1024
#define D_SZ 512
#define H_SZ 8

__device__ __forceinline__ void gload16(void* lds, const void* g) {
    typedef const __attribute__((address_space(1))) unsigned int* gp_t;
    typedef __attribute__((address_space(3))) unsigned int* lp_t;
    __builtin_amdgcn_global_load_lds((gp_t)g, (lp_t)lds, 16, 0, 0);
}

__device__ __forceinline__ unsigned int cvtpk(float lo, float hi) {
    unsigned int r;
    asm("v_cvt_pk_bf16_f32 %0, %1, %2" : "=v"(r) : "v"(lo), "v"(hi));
    return r;
}

__device__ __forceinline__ float fexp2(float x) {
    float r;
    asm("v_exp_f32 %0, %1" : "=v"(r) : "v"(x));
    return r;
}

// ---------------- f32 -> bf16 convert (vectorized) ----------------
struct alignas(8) B4 { bf16 a, b, c, d; };

__global__ void cvt4(const float* __restrict__ s, bf16* __restrict__ d, int n4) {
    int i = blockIdx.x * 256 + threadIdx.x;
    if (i < n4) {
        float4 v = ((const float4*)s)[i];
        B4 o;
        o.a = __float2bfloat16(v.x);
        o.b = __float2bfloat16(v.y);
        o.c = __float2bfloat16(v.z);
        o.d = __float2bfloat16(v.w);
        *(B4*)(d + (size_t)i * 4) = o;
    }
}

// ---------------- 512x512 transpose + convert: Wt[e][d] = bf16(W[d][e]) ----------------
__global__ void tpose4(const float* __restrict__ s0, const float* __restrict__ s1,
                       const float* __restrict__ s2, const float* __restrict__ s3,
                       bf16* __restrict__ d0, bf16* __restrict__ d1,
                       bf16* __restrict__ d2, bf16* __restrict__ d3) {
    __shared__ float t[32][33];
    const float* s = blockIdx.z == 0 ? s0 : blockIdx.z == 1 ? s1 : blockIdx.z == 2 ? s2 : s3;
    bf16* d = blockIdx.z == 0 ? d0 : blockIdx.z == 1 ? d1 : blockIdx.z == 2 ? d2 : d3;
    int tx = threadIdx.x, ty = threadIdx.y;  // 32 x 8
    int r0 = blockIdx.y * 32, c0 = blockIdx.x * 32;
#pragma unroll
    for (int i = 0; i < 32; i += 8)
        t[ty + i][tx] = s[(size_t)(r0 + ty + i) * 512 + c0 + tx];
    __syncthreads();
#pragma unroll
    for (int i = 0; i < 32; i += 8)
        d[(size_t)(c0 + ty + i) * 512 + r0 + tx] = __float2bfloat16(t[tx][ty + i]);
}

// ---------------- GEMM: C[M x 512] = A[M x 512] * W, A bf16, Wt[e][d] bf16 ----------------
template <int MODE>
__global__ __launch_bounds__(256) void gemm512(const bf16* __restrict__ A,
                                               const bf16* __restrict__ Bt,
                                               void* __restrict__ outp,
                                               const float* __restrict__ bias, int logS) {
    __shared__ bf16 lA[128 * 32];
    __shared__ bf16 lB[128 * 32];
    const int tid = threadIdx.x;
    const int wave = tid >> 6, lane = tid & 63;
    const int wr = wave >> 1, wc = wave & 1;
    const int g16 = lane >> 4, r16 = lane & 15;
    const long rowBase = (long)blockIdx.x * 128;
    const int colBase = blockIdx.y * 128;

    f32x4 acc[4][4];
#pragma unroll
    for (int m = 0; m < 4; ++m)
#pragma unroll
        for (int n = 0; n < 4; ++n) acc[m][n] = {0.f, 0.f, 0.f, 0.f};

    for (int k0 = 0; k0 < 512; k0 += 32) {
        __syncthreads();
#pragma unroll
        for (int half = 0; half < 2; ++half) {
            int cbase = half * 256 + wave * 64;
            int chunk = cbase + lane;
            int row = chunk >> 2;
            int kc = (chunk & 3) ^ (row & 3);
            gload16((char*)lA + cbase * 16, A + (rowBase + row) * 512 + k0 + kc * 8);
            gload16((char*)lB + cbase * 16, Bt + (long)(colBase + row) * 512 + k0 + kc * 8);
        }
        __syncthreads();
        short8 a[4], b[4];
#pragma unroll
        for (int m = 0; m < 4; ++m) {
            int row = wr * 64 + m * 16 + r16;
            a[m] = *(const short8*)((const char*)lA + row * 64 + ((g16 ^ (row & 3)) * 16));
        }
#pragma unroll
        for (int n = 0; n < 4; ++n) {
            int row = wc * 64 + n * 16 + r16;
            b[n] = *(const short8*)((const char*)lB + row * 64 + ((g16 ^ (row & 3)) * 16));
        }
#pragma unroll
        for (int m = 0; m < 4; ++m)
#pragma unroll
            for (int n = 0; n < 4; ++n)
                acc[m][n] = __builtin_amdgcn_mfma_f32_16x16x32_bf16(a[m], b[n], acc[m][n], 0, 0, 0);
    }

    const int S = 1 << logS;
#pragma unroll
    for (int m = 0; m < 4; ++m) {
#pragma unroll
        for (int r = 0; r < 4; ++r) {
            long gm = rowBase + wr * 64 + m * 16 + g16 * 4 + r;
            int bb = (int)(gm >> logS);
            int s = (int)gm & (S - 1);
#pragma unroll
            for (int n = 0; n < 4; ++n) {
                int e = colBase + wc * 64 + n * 16 + r16;
                float v = acc[m][n][r];
                if (MODE == 1) v += bias[(long)s * 512 + e];
                if (MODE == 3) {
                    ((float*)outp)[gm * 512 + e] = v + bias[e];
                } else {
                    int h = e >> 6, c = e & 63;
                    long idx;
                    if (MODE == 2)
                        idx = (((long)bb * H_SZ + h) * 64 + c) * (long)L_SZ + s;
                    else
                        idx = (((long)bb * H_SZ + h) * (long)S + s) * 64 + c;
                    ((bf16*)outp)[idx] = __float2bfloat16(v);
                }
            }
        }
    }
}

// ---------------- flash attention v2: swapped QK^T, 32x32 MFMA, in-register softmax ----
// block = 512 threads (8 waves), 256 q-rows per block, 2 blocks per (b,h).
// S^T[k][q] = mfma32(A=K[k][c], B=Q[q][c]); lane holds P[k 16 regs][q=lane&31].
// O^T[c][q] = mfma32(A=V^T[c][k], B=P^T built via cvt_pk + permlane32_swap).
__global__ __launch_bounds__(512, 4) void attn256(const bf16* __restrict__ q,
                                                  const bf16* __restrict__ k,
                                                  const bf16* __restrict__ vT,
                                                  const int* __restrict__ mask,
                                                  bf16* __restrict__ o) {
    __shared__ bf16 lK[2][32 * 64];   // [k 32][c 64], rows xor-swizzled by (k&7)
    __shared__ bf16 lV[2][64 * 32];   // [c 64][k 32], rows xor-swizzled by (c&3)
    __shared__ float lMf[1024];       // mask -> {0, -1e38}

    const int tid = threadIdx.x;
    const int wv = tid >> 6, lane = tid & 63;
    const int q32 = lane & 31, hi = lane >> 5;

    // XCD-aware decode: both q-chunks of a bh land on the same XCD
    const int wg = blockIdx.x;
    const int xcd = wg & 7, slot = wg >> 3;
    const int bh = xcd * 32 + (slot >> 1), qc = slot & 1;
    const int b = bh >> 3, h = bh & 7;

    const bf16* kbase = k + (long)bh * L_SZ * 64;
    const bf16* vbase = vT + (long)bh * 64 * L_SZ;

    // mask -> additive bias (exp2 domain)
    const int* mrow = mask + b * L_SZ;
    lMf[tid] = mrow[tid] ? -1e38f : 0.f;
    lMf[tid + 512] = mrow[tid + 512] ? -1e38f : 0.f;

    // staging: waves 0-3 stage K (4KB), waves 4-7 stage V (4KB); 1 gload16/thread/iter
    const bf16* gsrc;
    int gstep;
    char *dst0, *dst1;
    {
        int sc = (wv & 3) * 64 + lane;  // chunk 0..255
        if (wv < 4) {
            int r = sc >> 3, j = sc & 7, gj = j ^ (r & 7);
            gsrc = kbase + r * 64 + gj * 8;
            gstep = 32 * 64;
            dst0 = (char*)(&lK[0][0]) + wv * 1024;
            dst1 = (char*)(&lK[1][0]) + wv * 1024;
        } else {
            int c = sc >> 2, j = sc & 3, gj = j ^ (c & 3);
            gsrc = vbase + (long)c * L_SZ + gj * 8;
            gstep = 32;
            dst0 = (char*)(&lV[0][0]) + (wv - 4) * 1024;
            dst1 = (char*)(&lV[1][0]) + (wv - 4) * 1024;
        }
    }
    gload16(dst0, gsrc);  // kb = 0

    // Q fragments (B-operand: col=q, 8 contiguous c per lane-half), from global once
    const bf16* qp = q + ((long)bh * N_SZ + qc * 256 + wv * 32 + q32) * 64 + hi * 8;
    short8 qf[4];
#pragma unroll
    for (int t = 0; t < 4; ++t) qf[t] = *(const short8*)(qp + t * 16);

    float mrun = 0.f, lrun = 0.f;
    f32x16 oa0, oa1;
#pragma unroll
    for (int i = 0; i < 16; ++i) { oa0[i] = 0.f; oa1[i] = 0.f; }

    __syncthreads();

    const float CL = 0.18033688011112042f;  // SCALE * log2(e)

    for (int kb = 0; kb < 32; ++kb) {
        const char* curK = (const char*)(&lK[kb & 1][0]);
        const char* curV = (const char*)(&lV[kb & 1][0]);
        if (kb < 31) gload16((kb & 1) ? dst0 : dst1, gsrc + (long)(kb + 1) * gstep);

        // S^T = K . Q^T over c=64 (4 mfma32)
        f32x16 s;
#pragma unroll
        for (int i = 0; i < 16; ++i) s[i] = 0.f;
#pragma unroll
        for (int t = 0; t < 4; ++t) {
            short8 kf = *(const short8*)(curK + q32 * 128 + (((t * 2 + hi) ^ (q32 & 7)) * 16));
            s = __builtin_amdgcn_mfma_f32_32x32x16_bf16(kf, qf[t], s, 0, 0, 0);
        }

        // mask bias: reg i -> k_local = (i&3) + 8*(i>>2) + 4*hi
        const float* mf = lMf + kb * 32 + hi * 4;
        float4 mq0 = *(const float4*)(mf);
        float4 mq1 = *(const float4*)(mf + 8);
        float4 mq2 = *(const float4*)(mf + 16);
        float4 mq3 = *(const float4*)(mf + 24);
        float mb[16] = {mq0.x, mq0.y, mq0.z, mq0.w, mq1.x, mq1.y, mq1.z, mq1.w,
                        mq2.x, mq2.y, mq2.z, mq2.w, mq3.x, mq3.y, mq3.z, mq3.w};

        float t16[16];
#pragma unroll
        for (int i = 0; i < 16; ++i) t16[i] = fmaf(s[i], CL, mb[i]);

        // row max: in-lane tree + one cross-half swap
        float m8[8];
#pragma unroll
        for (int i = 0; i < 8; ++i) m8[i] = fmaxf(t16[i], t16[i + 8]);
        float tm = fmaxf(fmaxf(fmaxf(m8[0], m8[4]), fmaxf(m8[1], m8[5])),
                         fmaxf(fmaxf(m8[2], m8[6]), fmaxf(m8[3], m8[7])));
        tm = fmaxf(tm, __shfl_xor(tm, 32));
        float mnew = fmaxf(mrun, tm);
        float al = fexp2(mrun - mnew);
        mrun = mnew;

#pragma unroll
        for (int i = 0; i < 16; ++i) t16[i] = fexp2(t16[i] - mnew);
        float s8[8];
#pragma unroll
        for (int i = 0; i < 8; ++i) s8[i] = t16[i] + t16[i + 8];
        float ps = ((s8[0] + s8[4]) + (s8[1] + s8[5])) + ((s8[2] + s8[6]) + (s8[3] + s8[7]));
        ps += __shfl_xor(ps, 32);
        lrun = fmaf(lrun, al, ps);

#pragma unroll
        for (int i = 0; i < 16; ++i) { oa0[i] *= al; oa1[i] *= al; }

        // P -> bf16 B-fragments via cvt_pk + permlane32_swap.
        // permlane32_swap vdst,vsrc: vdst.hi32 <-> vsrc.lo32.
        // swap(x0,x2): x0 -> word0 {lo: k0,1 | hi: k8,9}, x2 -> word2 {lo: k4,5 | hi: k12,13}
        unsigned int x0 = cvtpk(t16[0], t16[1]), x1 = cvtpk(t16[2], t16[3]),
                     x2 = cvtpk(t16[4], t16[5]), x3 = cvtpk(t16[6], t16[7]),
                     x4 = cvtpk(t16[8], t16[9]), x5 = cvtpk(t16[10], t16[11]),
                     x6 = cvtpk(t16[12], t16[13]), x7 = cvtpk(t16[14], t16[15]);
        asm("v_permlane32_swap_b32 %0, %1" : "+v"(x0), "+v"(x2));
        asm("v_permlane32_swap_b32 %0, %1" : "+v"(x1), "+v"(x3));
        asm("v_permlane32_swap_b32 %0, %1" : "+v"(x4), "+v"(x6));
        asm("v_permlane32_swap_b32 %0, %1" : "+v"(x5), "+v"(x7));
        union U { unsigned int u[4]; short8 s8v; };
        U f1, f2;
        f1.u[0] = x0; f1.u[1] = x1; f1.u[2] = x2; f1.u[3] = x3;
        f2.u[0] = x4; f2.u[1] = x5; f2.u[2] = x6; f2.u[3] = x7;

        // O^T += V^T . P^T  (2 c-tiles x 2 k-halves)
#pragma unroll
        for (int kt = 0; kt < 2; ++kt) {
            short8 pf = kt ? f2.s8v : f1.s8v;
            int sw = ((kt * 2 + hi) ^ (q32 & 3)) * 16;
            short8 v0 = *(const short8*)(curV + (q32)*64 + sw);
            short8 v1 = *(const short8*)(curV + (32 + q32) * 64 + sw);
            oa0 = __builtin_amdgcn_mfma_f32_32x32x16_bf16(v0, pf, oa0, 0, 0, 0);
            oa1 = __builtin_amdgcn_mfma_f32_32x32x16_bf16(v1, pf, oa1, 0, 0, 0);
        }

        __syncthreads();
    }

    // epilogue: O^T[c][q] -> o[b][q][h*64 + c], c = (reg&3) + 8*(reg>>2) + 4*hi + 32*ct
    float inv = 1.f / lrun;
    bf16* op = o + ((long)b * N_SZ + qc * 256 + wv * 32 + q32) * 512 + h * 64;
#pragma unroll
    for (int ct = 0; ct < 2; ++ct) {
#pragma unroll
        for (int rq = 0; rq < 4; ++rq) {
            int c0 = ct * 32 + rq * 8 + hi * 4;
            float v0 = (ct ? oa1[rq * 4 + 0] : oa0[rq * 4 + 0]) * inv;
            float v1 = (ct ? oa1[rq * 4 + 1] : oa0[rq * 4 + 1]) * inv;
            float v2 = (ct ? oa1[rq * 4 + 2] : oa0[rq * 4 + 2]) * inv;
            float v3 = (ct ? oa1[rq * 4 + 3] : oa0[rq * 4 + 3]) * inv;
            uint2 st;
            st.x = cvtpk(v0, v1);
            st.y = cvtpk(v2, v3);
            *(uint2*)(op + c0) = st;
        }
    }
}

extern "C" void kernel_launch(void* const* d_in, const int* in_sizes, int n_in,
                              void* d_out, int out_size, void* d_ws, size_t ws_size,
                              hipStream_t stream) {
    const float* x_q  = (const float*)d_in[0];
    const float* x_kv = (const float*)d_in[1];
    const int*   mask = (const int*)d_in[2];
    const float* Wq   = (const float*)d_in[3];
    const float* Wk   = (const float*)d_in[4];
    const float* Wv   = (const float*)d_in[5];
    const float* Wo   = (const float*)d_in[6];
    const float* bo   = (const float*)d_in[7];
    const float* rpb  = (const float*)d_in[8];
    float* out = (float*)d_out;

    char* w = (char*)d_ws;
    bf16* xq_bf  = (bf16*)(w + 0);           // reused as o_bf after attention
    bf16* xkv_bf = (bf16*)(w + 16777216);
    bf16* WqT    = (bf16*)(w + 50331648);
    bf16* WkT    = WqT + 262144;
    bf16* WvT    = WkT + 262144;
    bf16* WoT    = WvT + 262144;
    bf16* qh     = (bf16*)(w + 52428800);    // [b][h][n][c]
    bf16* kh     = (bf16*)(w + 69206016);    // [b][h][l][c]
    bf16* vTh    = (bf16*)(w + 102760448);   // [b][h][c][l]
    bf16* o_bf   = xq_bf;

    cvt4<<<8192, 256, 0, stream>>>(x_q, xq_bf, 2097152);
    cvt4<<<16384, 256, 0, stream>>>(x_kv, xkv_bf, 4194304);
    tpose4<<<dim3(16, 16, 4), dim3(32, 8), 0, stream>>>(Wq, Wk, Wv, Wo, WqT, WkT, WvT, WoT);

    gemm512<0><<<dim3(128, 4), 256, 0, stream>>>(xq_bf, WqT, qh, nullptr, 9);
    gemm512<1><<<dim3(256, 4), 256, 0, stream>>>(xkv_bf, WkT, kh, rpb, 10);
    gemm512<2><<<dim3(256, 4), 256, 0, stream>>>(xkv_bf, WvT, vTh, nullptr, 10);

    attn256<<<512, 512, 0, stream>>>(qh, kh, vTh, mask, o_bf);

    gemm512<3><<<dim3(128, 4), 256, 0, stream>>>(o_bf, WoT, out, bo, 9);
}

// Round 4
// 187.705 us; speedup vs baseline: 1.4515x; 1.1675x over previous
//
#include <hip/hip_runtime.h>
#include <hip/hip_bf16.h>

typedef __hip_bfloat16 bf16;
typedef __attribute__((ext_vector_type(8))) short short8;
typedef __attribute__((ext_vector_type(4))) float f32x4;
typedef __attribute__((ext_vector_type(16))) float f32x16;

#define B_SZ 32
#define N_SZ 512
#define L_SZ 1024
#define D_SZ 512
#define H_SZ 8

__device__ __forceinline__ void gload16(void* lds, const void* g) {
    typedef const __attribute__((address_space(1))) unsigned int* gp_t;
    typedef __attribute__((address_space(3))) unsigned int* lp_t;
    __builtin_amdgcn_global_load_lds((gp_t)g, (lp_t)lds, 16, 0, 0);
}

__device__ __forceinline__ unsigned int cvtpk(float lo, float hi) {
    unsigned int r;
    asm("v_cvt_pk_bf16_f32 %0, %1, %2" : "=v"(r) : "v"(lo), "v"(hi));
    return r;
}

__device__ __forceinline__ float fexp2(float x) {
    float r;
    asm("v_exp_f32 %0, %1" : "=v"(r) : "v"(x));
    return r;
}

// ---------------- f32 -> bf16 convert (vectorized) ----------------
struct alignas(8) B4 { bf16 a, b, c, d; };

__global__ void cvt4(const float* __restrict__ s, bf16* __restrict__ d, int n4) {
    int i = blockIdx.x * 256 + threadIdx.x;
    if (i < n4) {
        float4 v = ((const float4*)s)[i];
        B4 o;
        o.a = __float2bfloat16(v.x);
        o.b = __float2bfloat16(v.y);
        o.c = __float2bfloat16(v.z);
        o.d = __float2bfloat16(v.w);
        *(B4*)(d + (size_t)i * 4) = o;
    }
}

// ---------------- 512x512 transpose + convert: Wt[e][d] = bf16(W[d][e]) ----------------
__global__ void tpose4(const float* __restrict__ s0, const float* __restrict__ s1,
                       const float* __restrict__ s2, const float* __restrict__ s3,
                       bf16* __restrict__ d0, bf16* __restrict__ d1,
                       bf16* __restrict__ d2, bf16* __restrict__ d3) {
    __shared__ float t[32][33];
    const float* s = blockIdx.z == 0 ? s0 : blockIdx.z == 1 ? s1 : blockIdx.z == 2 ? s2 : s3;
    bf16* d = blockIdx.z == 0 ? d0 : blockIdx.z == 1 ? d1 : blockIdx.z == 2 ? d2 : d3;
    int tx = threadIdx.x, ty = threadIdx.y;  // 32 x 8
    int r0 = blockIdx.y * 32, c0 = blockIdx.x * 32;
#pragma unroll
    for (int i = 0; i < 32; i += 8)
        t[ty + i][tx] = s[(size_t)(r0 + ty + i) * 512 + c0 + tx];
    __syncthreads();
#pragma unroll
    for (int i = 0; i < 32; i += 8)
        d[(size_t)(c0 + ty + i) * 512 + r0 + tx] = __float2bfloat16(t[tx][ty + i]);
}

// ---------------- GEMM: C[M x 512] = A[M x 512] * Bt^T, BK=64 ----------------
// MODE 0: Q  -> bf16 head-split [b][h][s][c]          (rows = b*N+s, logS=9)
// MODE 1: K  -> bf16 head-split [b][h][s][c] + rpb    (rows = b*L+s, logS=10)
// MODE 2: V^T-> rows = e (512), cols = global l; out vT [b][h][c][l]
// MODE 3: O  -> f32 row-major [m][e] + bo
template <int MODE>
__global__ __launch_bounds__(256) void gemm512(const bf16* __restrict__ A,
                                               const bf16* __restrict__ Bt,
                                               void* __restrict__ outp,
                                               const float* __restrict__ bias, int logS) {
    __shared__ bf16 lA[128 * 64];
    __shared__ bf16 lB[128 * 64];
    const int tid = threadIdx.x;
    const int wave = tid >> 6, lane = tid & 63;
    const int wr = wave >> 1, wc = wave & 1;
    const int g16 = lane >> 4, r16 = lane & 15;
    const long rowBase = (long)blockIdx.x * 128;
    const int colBase = blockIdx.y * 128;

    f32x4 acc[4][4];
#pragma unroll
    for (int m = 0; m < 4; ++m)
#pragma unroll
        for (int n = 0; n < 4; ++n) acc[m][n] = {0.f, 0.f, 0.f, 0.f};

    for (int k0 = 0; k0 < 512; k0 += 64) {
        __syncthreads();
        // stage 16KB A + 16KB B: chunk = row*8 + slot; swizzled global source, linear dest
#pragma unroll
        for (int rnd = 0; rnd < 4; ++rnd) {
            int chunk = rnd * 256 + tid;  // 0..1023
            int row = chunk >> 3, j = chunk & 7, gj = j ^ (row & 7);
            gload16((char*)lA + chunk * 16, A + (rowBase + row) * 512 + k0 + gj * 8);
            gload16((char*)lB + chunk * 16, Bt + (long)(colBase + row) * 512 + k0 + gj * 8);
        }
        __syncthreads();
#pragma unroll
        for (int kk = 0; kk < 2; ++kk) {
            short8 a[4], b[4];
#pragma unroll
            for (int m = 0; m < 4; ++m) {
                int row = wr * 64 + m * 16 + r16;
                a[m] = *(const short8*)((const char*)lA + row * 128 +
                                        (((kk * 4 + g16) ^ (row & 7)) * 16));
            }
#pragma unroll
            for (int n = 0; n < 4; ++n) {
                int row = wc * 64 + n * 16 + r16;
                b[n] = *(const short8*)((const char*)lB + row * 128 +
                                        (((kk * 4 + g16) ^ (row & 7)) * 16));
            }
#pragma unroll
            for (int m = 0; m < 4; ++m)
#pragma unroll
                for (int n = 0; n < 4; ++n)
                    acc[m][n] =
                        __builtin_amdgcn_mfma_f32_16x16x32_bf16(a[m], b[n], acc[m][n], 0, 0, 0);
        }
    }

    const int S = 1 << logS;
#pragma unroll
    for (int m = 0; m < 4; ++m) {
#pragma unroll
        for (int r = 0; r < 4; ++r) {
            long gm = rowBase + wr * 64 + m * 16 + g16 * 4 + r;
            if (MODE == 2) {
                int e = (int)gm;
                int h = e >> 6, c = e & 63;
#pragma unroll
                for (int n = 0; n < 4; ++n) {
                    int gl = colBase + wc * 64 + n * 16 + r16;
                    int bb = gl >> 10, s = gl & 1023;
                    long idx = (((long)bb * H_SZ + h) * 64 + c) * (long)L_SZ + s;
                    ((bf16*)outp)[idx] = __float2bfloat16(acc[m][n][r]);
                }
            } else {
                int bb = (int)(gm >> logS);
                int s = (int)gm & (S - 1);
#pragma unroll
                for (int n = 0; n < 4; ++n) {
                    int e = colBase + wc * 64 + n * 16 + r16;
                    float v = acc[m][n][r];
                    if (MODE == 1) v += bias[(long)s * 512 + e];
                    if (MODE == 3) {
                        ((float*)outp)[gm * 512 + e] = v + bias[e];
                    } else {
                        int h = e >> 6, c = e & 63;
                        long idx = (((long)bb * H_SZ + h) * (long)S + s) * 64 + c;
                        ((bf16*)outp)[idx] = __float2bfloat16(v);
                    }
                }
            }
        }
    }
}

// ---------------- flash attention: swapped QK^T, 32x32 MFMA, in-register softmax ----
__global__ __launch_bounds__(512, 4) void attn256(const bf16* __restrict__ q,
                                                  const bf16* __restrict__ k,
                                                  const bf16* __restrict__ vT,
                                                  const int* __restrict__ mask,
                                                  bf16* __restrict__ o) {
    __shared__ bf16 lK[2][32 * 64];   // [k 32][c 64], rows xor-swizzled by (k&7)
    __shared__ bf16 lV[2][64 * 32];   // [c 64][k 32], rows xor-swizzled by (c&3)
    __shared__ float lMf[1024];       // mask -> {0, -1e38}

    const int tid = threadIdx.x;
    const int wv = tid >> 6, lane = tid & 63;
    const int q32 = lane & 31, hi = lane >> 5;

    const int wg = blockIdx.x;
    const int xcd = wg & 7, slot = wg >> 3;
    const int bh = xcd * 32 + (slot >> 1), qc = slot & 1;
    const int b = bh >> 3, h = bh & 7;

    const bf16* kbase = k + (long)bh * L_SZ * 64;
    const bf16* vbase = vT + (long)bh * 64 * L_SZ;

    const int* mrow = mask + b * L_SZ;
    lMf[tid] = mrow[tid] ? -1e38f : 0.f;
    lMf[tid + 512] = mrow[tid + 512] ? -1e38f : 0.f;

    const bf16* gsrc;
    int gstep;
    char *dst0, *dst1;
    {
        int sc = (wv & 3) * 64 + lane;
        if (wv < 4) {
            int r = sc >> 3, j = sc & 7, gj = j ^ (r & 7);
            gsrc = kbase + r * 64 + gj * 8;
            gstep = 32 * 64;
            dst0 = (char*)(&lK[0][0]) + wv * 1024;
            dst1 = (char*)(&lK[1][0]) + wv * 1024;
        } else {
            int c = sc >> 2, j = sc & 3, gj = j ^ (c & 3);
            gsrc = vbase + (long)c * L_SZ + gj * 8;
            gstep = 32;
            dst0 = (char*)(&lV[0][0]) + (wv - 4) * 1024;
            dst1 = (char*)(&lV[1][0]) + (wv - 4) * 1024;
        }
    }
    gload16(dst0, gsrc);  // kb = 0

    const bf16* qp = q + ((long)bh * N_SZ + qc * 256 + wv * 32 + q32) * 64 + hi * 8;
    short8 qf[4];
#pragma unroll
    for (int t = 0; t < 4; ++t) qf[t] = *(const short8*)(qp + t * 16);

    float mrun = 0.f, lrun = 0.f;
    f32x16 oa0, oa1;
#pragma unroll
    for (int i = 0; i < 16; ++i) { oa0[i] = 0.f; oa1[i] = 0.f; }

    __syncthreads();

    const float CL = 0.18033688011112042f;  // SCALE * log2(e)

    for (int kb = 0; kb < 32; ++kb) {
        const char* curK = (const char*)(&lK[kb & 1][0]);
        const char* curV = (const char*)(&lV[kb & 1][0]);
        if (kb < 31) gload16((kb & 1) ? dst0 : dst1, gsrc + (long)(kb + 1) * gstep);

        // S^T = K . Q^T over c=64 (4 mfma32)
        f32x16 s;
#pragma unroll
        for (int i = 0; i < 16; ++i) s[i] = 0.f;
#pragma unroll
        for (int t = 0; t < 4; ++t) {
            short8 kf = *(const short8*)(curK + q32 * 128 + (((t * 2 + hi) ^ (q32 & 7)) * 16));
            s = __builtin_amdgcn_mfma_f32_32x32x16_bf16(kf, qf[t], s, 0, 0, 0);
        }

        // mask bias: reg i -> k_local = (i&3) + 8*(i>>2) + 4*hi
        const float* mf = lMf + kb * 32 + hi * 4;
        float4 mq0 = *(const float4*)(mf);
        float4 mq1 = *(const float4*)(mf + 8);
        float4 mq2 = *(const float4*)(mf + 16);
        float4 mq3 = *(const float4*)(mf + 24);
        float mb[16] = {mq0.x, mq0.y, mq0.z, mq0.w, mq1.x, mq1.y, mq1.z, mq1.w,
                        mq2.x, mq2.y, mq2.z, mq2.w, mq3.x, mq3.y, mq3.z, mq3.w};

        float t16[16];
#pragma unroll
        for (int i = 0; i < 16; ++i) t16[i] = fmaf(s[i], CL, mb[i]);

        // row max of this tile
        float m8[8];
#pragma unroll
        for (int i = 0; i < 8; ++i) m8[i] = fmaxf(t16[i], t16[i + 8]);
        float tm = fmaxf(fmaxf(fmaxf(m8[0], m8[4]), fmaxf(m8[1], m8[5])),
                         fmaxf(fmaxf(m8[2], m8[6]), fmaxf(m8[3], m8[7])));
        tm = fmaxf(tm, __shfl_xor(tm, 32));

        // defer-max (T13): rescale only if tile max exceeds running max + 8 (log2 domain)
        if (__any(tm > mrun + 8.f)) {
            float mnew = fmaxf(mrun, tm);
            float al = fexp2(mrun - mnew);
            mrun = mnew;
            lrun *= al;
#pragma unroll
            for (int i = 0; i < 16; ++i) { oa0[i] *= al; oa1[i] *= al; }
        }

#pragma unroll
        for (int i = 0; i < 16; ++i) t16[i] = fexp2(t16[i] - mrun);
        float s8[8];
#pragma unroll
        for (int i = 0; i < 8; ++i) s8[i] = t16[i] + t16[i + 8];
        float ps = ((s8[0] + s8[4]) + (s8[1] + s8[5])) + ((s8[2] + s8[6]) + (s8[3] + s8[7]));
        ps += __shfl_xor(ps, 32);
        lrun += ps;

        // P -> bf16 B-fragments via cvt_pk + permlane32_swap
        unsigned int x0 = cvtpk(t16[0], t16[1]), x1 = cvtpk(t16[2], t16[3]),
                     x2 = cvtpk(t16[4], t16[5]), x3 = cvtpk(t16[6], t16[7]),
                     x4 = cvtpk(t16[8], t16[9]), x5 = cvtpk(t16[10], t16[11]),
                     x6 = cvtpk(t16[12], t16[13]), x7 = cvtpk(t16[14], t16[15]);
        asm("v_permlane32_swap_b32 %0, %1" : "+v"(x0), "+v"(x2));
        asm("v_permlane32_swap_b32 %0, %1" : "+v"(x1), "+v"(x3));
        asm("v_permlane32_swap_b32 %0, %1" : "+v"(x4), "+v"(x6));
        asm("v_permlane32_swap_b32 %0, %1" : "+v"(x5), "+v"(x7));
        union U { unsigned int u[4]; short8 s8v; };
        U f1, f2;
        f1.u[0] = x0; f1.u[1] = x1; f1.u[2] = x2; f1.u[3] = x3;
        f2.u[0] = x4; f2.u[1] = x5; f2.u[2] = x6; f2.u[3] = x7;

        // O^T += V^T . P^T  (2 c-tiles x 2 k-halves)
#pragma unroll
        for (int kt = 0; kt < 2; ++kt) {
            short8 pf = kt ? f2.s8v : f1.s8v;
            int sw = ((kt * 2 + hi) ^ (q32 & 3)) * 16;
            short8 v0 = *(const short8*)(curV + (q32)*64 + sw);
            short8 v1 = *(const short8*)(curV + (32 + q32) * 64 + sw);
            oa0 = __builtin_amdgcn_mfma_f32_32x32x16_bf16(v0, pf, oa0, 0, 0, 0);
            oa1 = __builtin_amdgcn_mfma_f32_32x32x16_bf16(v1, pf, oa1, 0, 0, 0);
        }

        __syncthreads();
    }

    // epilogue: O^T[c][q] -> o[b][q][h*64 + c]
    float inv = 1.f / lrun;
    bf16* op = o + ((long)b * N_SZ + qc * 256 + wv * 32 + q32) * 512 + h * 64;
#pragma unroll
    for (int ct = 0; ct < 2; ++ct) {
#pragma unroll
        for (int rq = 0; rq < 4; ++rq) {
            int c0 = ct * 32 + rq * 8 + hi * 4;
            float v0 = (ct ? oa1[rq * 4 + 0] : oa0[rq * 4 + 0]) * inv;
            float v1 = (ct ? oa1[rq * 4 + 1] : oa0[rq * 4 + 1]) * inv;
            float v2 = (ct ? oa1[rq * 4 + 2] : oa0[rq * 4 + 2]) * inv;
            float v3 = (ct ? oa1[rq * 4 + 3] : oa0[rq * 4 + 3]) * inv;
            uint2 st;
            st.x = cvtpk(v0, v1);
            st.y = cvtpk(v2, v3);
            *(uint2*)(op + c0) = st;
        }
    }
}

extern "C" void kernel_launch(void* const* d_in, const int* in_sizes, int n_in,
                              void* d_out, int out_size, void* d_ws, size_t ws_size,
                              hipStream_t stream) {
    const float* x_q  = (const float*)d_in[0];
    const float* x_kv = (const float*)d_in[1];
    const int*   mask = (const int*)d_in[2];
    const float* Wq   = (const float*)d_in[3];
    const float* Wk   = (const float*)d_in[4];
    const float* Wv   = (const float*)d_in[5];
    const float* Wo   = (const float*)d_in[6];
    const float* bo   = (const float*)d_in[7];
    const float* rpb  = (const float*)d_in[8];
    float* out = (float*)d_out;

    char* w = (char*)d_ws;
    bf16* xq_bf  = (bf16*)(w + 0);           // reused as o_bf after attention
    bf16* xkv_bf = (bf16*)(w + 16777216);
    bf16* WqT    = (bf16*)(w + 50331648);
    bf16* WkT    = WqT + 262144;
    bf16* WvT    = WkT + 262144;
    bf16* WoT    = WvT + 262144;
    bf16* qh     = (bf16*)(w + 52428800);    // [b][h][n][c]
    bf16* kh     = (bf16*)(w + 69206016);    // [b][h][l][c]
    bf16* vTh    = (bf16*)(w + 102760448);   // [b][h][c][l]
    bf16* o_bf   = xq_bf;

    cvt4<<<8192, 256, 0, stream>>>(x_q, xq_bf, 2097152);
    cvt4<<<16384, 256, 0, stream>>>(x_kv, xkv_bf, 4194304);
    tpose4<<<dim3(16, 16, 4), dim3(32, 8), 0, stream>>>(Wq, Wk, Wv, Wo, WqT, WkT, WvT, WoT);

    gemm512<0><<<dim3(128, 4), 256, 0, stream>>>(xq_bf, WqT, qh, nullptr, 9);
    gemm512<1><<<dim3(256, 4), 256, 0, stream>>>(xkv_bf, WkT, kh, rpb, 10);
    // V^T directly: A = WvT (512 rows), B-operand = x_kv rows (k-contiguous)
    gemm512<2><<<dim3(4, 256), 256, 0, stream>>>(WvT, xkv_bf, vTh, nullptr, 10);

    attn256<<<512, 512, 0, stream>>>(qh, kh, vTh, mask, o_bf);

    gemm512<3><<<dim3(128, 4), 256, 0, stream>>>(o_bf, WoT, out, bo, 9);
}

// Round 5
// 184.743 us; speedup vs baseline: 1.4748x; 1.0160x over previous
//
#include <hip/hip_runtime.h>
#include <hip/hip_bf16.h>

typedef __hip_bfloat16 bf16;
typedef __attribute__((ext_vector_type(8))) short short8;
typedef __attribute__((ext_vector_type(4))) float f32x4;
typedef __attribute__((ext_vector_type(16))) float f32x16;

#define B_SZ 32
#define N_SZ 512
#define L_SZ 1024
#define D_SZ 512
#define H_SZ 8

__device__ __forceinline__ void gload16(void* lds, const void* g) {
    typedef const __attribute__((address_space(1))) unsigned int* gp_t;
    typedef __attribute__((address_space(3))) unsigned int* lp_t;
    __builtin_amdgcn_global_load_lds((gp_t)g, (lp_t)lds, 16, 0, 0);
}

__device__ __forceinline__ unsigned int cvtpk(float lo, float hi) {
    unsigned int r;
    asm("v_cvt_pk_bf16_f32 %0, %1, %2" : "=v"(r) : "v"(lo), "v"(hi));
    return r;
}

__device__ __forceinline__ float fexp2(float x) {
    float r;
    asm("v_exp_f32 %0, %1" : "=v"(r) : "v"(x));
    return r;
}

// ---------------- f32 -> bf16 convert (both inputs, one dispatch) ----------------
struct alignas(8) B4 { bf16 a, b, c, d; };

__global__ void cvt_all(const float* __restrict__ xq, const float* __restrict__ xkv,
                        bf16* __restrict__ dq, bf16* __restrict__ dkv) {
    int i = blockIdx.x * 256 + threadIdx.x;
    const float* s;
    bf16* d;
    if (i < 2097152) {
        s = xq; d = dq;
    } else {
        i -= 2097152; s = xkv; d = dkv;
    }
    float4 v = ((const float4*)s)[i];
    B4 o;
    o.a = __float2bfloat16(v.x);
    o.b = __float2bfloat16(v.y);
    o.c = __float2bfloat16(v.z);
    o.d = __float2bfloat16(v.w);
    *(B4*)(d + (size_t)i * 4) = o;
}

// ---------------- 512x512 transpose + convert: Wt[e][d] = bf16(W[d][e]) ----------------
__global__ void tpose4(const float* __restrict__ s0, const float* __restrict__ s1,
                       const float* __restrict__ s2, const float* __restrict__ s3,
                       bf16* __restrict__ d0, bf16* __restrict__ d1,
                       bf16* __restrict__ d2, bf16* __restrict__ d3) {
    __shared__ float t[32][33];
    const float* s = blockIdx.z == 0 ? s0 : blockIdx.z == 1 ? s1 : blockIdx.z == 2 ? s2 : s3;
    bf16* d = blockIdx.z == 0 ? d0 : blockIdx.z == 1 ? d1 : blockIdx.z == 2 ? d2 : d3;
    int tx = threadIdx.x, ty = threadIdx.y;  // 32 x 8
    int r0 = blockIdx.y * 32, c0 = blockIdx.x * 32;
#pragma unroll
    for (int i = 0; i < 32; i += 8)
        t[ty + i][tx] = s[(size_t)(r0 + ty + i) * 512 + c0 + tx];
    __syncthreads();
#pragma unroll
    for (int i = 0; i < 32; i += 8)
        d[(size_t)(c0 + ty + i) * 512 + r0 + tx] = __float2bfloat16(t[tx][ty + i]);
}

// ---------------- fused QKV projection: 2560 blocks, runtime mode ----------------
// mode 0 (blocks 0-511):    Q = xq * WqT^T   -> qh [b][h][n][c]
// mode 1 (blocks 512-1535): K = xkv * WkT^T + rpb -> kh [b][h][l][c]
// mode 2 (blocks 1536-2559): V^T = WvT * xkv^T    -> vTh [b][h][c][l]
__global__ __launch_bounds__(256) void gemm_qkv(
    const bf16* __restrict__ xq, const bf16* __restrict__ xkv,
    const bf16* __restrict__ WqT, const bf16* __restrict__ WkT,
    const bf16* __restrict__ WvT, const float* __restrict__ rpb,
    bf16* __restrict__ qh, bf16* __restrict__ kh, bf16* __restrict__ vTh) {
    __shared__ bf16 lA[128 * 64];
    __shared__ bf16 lB[128 * 64];
    const int tid = threadIdx.x;
    const int wave = tid >> 6, lane = tid & 63;
    const int wr = wave >> 1, wc = wave & 1;
    const int g16 = lane >> 4, r16 = lane & 15;

    int bid = blockIdx.x;
    int mode;
    long rowBase;
    int colBase;
    const bf16 *A, *Bt;
    if (bid < 512) {
        mode = 0; A = xq; Bt = WqT;
        rowBase = (long)(bid >> 2) * 128; colBase = (bid & 3) * 128;
    } else if (bid < 1536) {
        mode = 1; int t = bid - 512; A = xkv; Bt = WkT;
        rowBase = (long)(t >> 2) * 128; colBase = (t & 3) * 128;
    } else {
        mode = 2; int t = bid - 1536; A = WvT; Bt = xkv;
        rowBase = (long)(t & 3) * 128; colBase = (t >> 2) * 128;
    }

    f32x4 acc[4][4];
#pragma unroll
    for (int m = 0; m < 4; ++m)
#pragma unroll
        for (int n = 0; n < 4; ++n) acc[m][n] = {0.f, 0.f, 0.f, 0.f};

    for (int k0 = 0; k0 < 512; k0 += 64) {
        __syncthreads();
#pragma unroll
        for (int rnd = 0; rnd < 4; ++rnd) {
            int chunk = rnd * 256 + tid;  // 0..1023
            int row = chunk >> 3, j = chunk & 7, gj = j ^ (row & 7);
            gload16((char*)lA + chunk * 16, A + (rowBase + row) * 512 + k0 + gj * 8);
            gload16((char*)lB + chunk * 16, Bt + (long)(colBase + row) * 512 + k0 + gj * 8);
        }
        __syncthreads();
#pragma unroll
        for (int kk = 0; kk < 2; ++kk) {
            short8 a[4], b[4];
#pragma unroll
            for (int m = 0; m < 4; ++m) {
                int row = wr * 64 + m * 16 + r16;
                a[m] = *(const short8*)((const char*)lA + row * 128 +
                                        (((kk * 4 + g16) ^ (row & 7)) * 16));
            }
#pragma unroll
            for (int n = 0; n < 4; ++n) {
                int row = wc * 64 + n * 16 + r16;
                b[n] = *(const short8*)((const char*)lB + row * 128 +
                                        (((kk * 4 + g16) ^ (row & 7)) * 16));
            }
#pragma unroll
            for (int m = 0; m < 4; ++m)
#pragma unroll
                for (int n = 0; n < 4; ++n)
                    acc[m][n] =
                        __builtin_amdgcn_mfma_f32_16x16x32_bf16(a[m], b[n], acc[m][n], 0, 0, 0);
        }
    }

#pragma unroll
    for (int m = 0; m < 4; ++m) {
#pragma unroll
        for (int r = 0; r < 4; ++r) {
            long gm = rowBase + wr * 64 + m * 16 + g16 * 4 + r;
            if (mode == 2) {
                int e = (int)gm;
                int hh = e >> 6, c = e & 63;
#pragma unroll
                for (int n = 0; n < 4; ++n) {
                    int gl = colBase + wc * 64 + n * 16 + r16;
                    int bb = gl >> 10, s = gl & 1023;
                    vTh[(((long)bb * H_SZ + hh) * 64 + c) * (long)L_SZ + s] =
                        __float2bfloat16(acc[m][n][r]);
                }
            } else if (mode == 1) {
                int bb = (int)(gm >> 10), s = (int)gm & 1023;
#pragma unroll
                for (int n = 0; n < 4; ++n) {
                    int e = colBase + wc * 64 + n * 16 + r16;
                    float v = acc[m][n][r] + rpb[(long)s * 512 + e];
                    int hh = e >> 6, c = e & 63;
                    kh[(((long)bb * H_SZ + hh) * (long)L_SZ + s) * 64 + c] = __float2bfloat16(v);
                }
            } else {
                int bb = (int)(gm >> 9), s = (int)gm & 511;
#pragma unroll
                for (int n = 0; n < 4; ++n) {
                    int e = colBase + wc * 64 + n * 16 + r16;
                    int hh = e >> 6, c = e & 63;
                    qh[(((long)bb * H_SZ + hh) * (long)N_SZ + s) * 64 + c] =
                        __float2bfloat16(acc[m][n][r]);
                }
            }
        }
    }
}

// ---------------- O projection: C[M x 512] = A * WoT^T + bo (f32 out) ----------------
__global__ __launch_bounds__(256) void gemm_o(const bf16* __restrict__ A,
                                              const bf16* __restrict__ Bt,
                                              float* __restrict__ outp,
                                              const float* __restrict__ bias) {
    __shared__ bf16 lA[128 * 64];
    __shared__ bf16 lB[128 * 64];
    const int tid = threadIdx.x;
    const int wave = tid >> 6, lane = tid & 63;
    const int wr = wave >> 1, wc = wave & 1;
    const int g16 = lane >> 4, r16 = lane & 15;
    const long rowBase = (long)blockIdx.x * 128;
    const int colBase = blockIdx.y * 128;

    f32x4 acc[4][4];
#pragma unroll
    for (int m = 0; m < 4; ++m)
#pragma unroll
        for (int n = 0; n < 4; ++n) acc[m][n] = {0.f, 0.f, 0.f, 0.f};

    for (int k0 = 0; k0 < 512; k0 += 64) {
        __syncthreads();
#pragma unroll
        for (int rnd = 0; rnd < 4; ++rnd) {
            int chunk = rnd * 256 + tid;
            int row = chunk >> 3, j = chunk & 7, gj = j ^ (row & 7);
            gload16((char*)lA + chunk * 16, A + (rowBase + row) * 512 + k0 + gj * 8);
            gload16((char*)lB + chunk * 16, Bt + (long)(colBase + row) * 512 + k0 + gj * 8);
        }
        __syncthreads();
#pragma unroll
        for (int kk = 0; kk < 2; ++kk) {
            short8 a[4], b[4];
#pragma unroll
            for (int m = 0; m < 4; ++m) {
                int row = wr * 64 + m * 16 + r16;
                a[m] = *(const short8*)((const char*)lA + row * 128 +
                                        (((kk * 4 + g16) ^ (row & 7)) * 16));
            }
#pragma unroll
            for (int n = 0; n < 4; ++n) {
                int row = wc * 64 + n * 16 + r16;
                b[n] = *(const short8*)((const char*)lB + row * 128 +
                                        (((kk * 4 + g16) ^ (row & 7)) * 16));
            }
#pragma unroll
            for (int m = 0; m < 4; ++m)
#pragma unroll
                for (int n = 0; n < 4; ++n)
                    acc[m][n] =
                        __builtin_amdgcn_mfma_f32_16x16x32_bf16(a[m], b[n], acc[m][n], 0, 0, 0);
        }
    }

#pragma unroll
    for (int m = 0; m < 4; ++m) {
#pragma unroll
        for (int r = 0; r < 4; ++r) {
            long gm = rowBase + wr * 64 + m * 16 + g16 * 4 + r;
#pragma unroll
            for (int n = 0; n < 4; ++n) {
                int e = colBase + wc * 64 + n * 16 + r16;
                outp[gm * 512 + e] = acc[m][n][r] + bias[e];
            }
        }
    }
}

// ---------------- flash attention: KVBLK=64, swapped QK^T, in-register softmax ----
__global__ __launch_bounds__(512, 4) void attn256(const bf16* __restrict__ q,
                                                  const bf16* __restrict__ k,
                                                  const bf16* __restrict__ vT,
                                                  const int* __restrict__ mask,
                                                  bf16* __restrict__ o) {
    __shared__ bf16 lK[2][64 * 64];   // [k 64][c 64], row slots xor-swizzled by (k&7)
    __shared__ bf16 lV[2][64 * 64];   // [c 64][k 64], row slots xor-swizzled by (c&7)
    __shared__ float lMf[1024];       // mask -> {0, -1e38}

    const int tid = threadIdx.x;
    const int wv = tid >> 6, lane = tid & 63;
    const int q32 = lane & 31, hi = lane >> 5;

    const int wg = blockIdx.x;
    const int xcd = wg & 7, slot = wg >> 3;
    const int bh = xcd * 32 + (slot >> 1), qc = slot & 1;
    const int b = bh >> 3, h = bh & 7;

    const bf16* kbase = k + (long)bh * L_SZ * 64;
    const bf16* vbase = vT + (long)bh * 64 * L_SZ;

    const int* mrow = mask + b * L_SZ;
    lMf[tid] = mrow[tid] ? -1e38f : 0.f;
    lMf[tid + 512] = mrow[tid + 512] ? -1e38f : 0.f;

    // staging: each thread 1 K-chunk + 1 V-chunk (16B) per 64-tile
    const int r_ = tid >> 3, j_ = tid & 7;
    const int gj_ = (j_ ^ (r_ & 7)) * 8;
    const bf16* gK = kbase + r_ * 64 + gj_;           // +4096 per tile
    const bf16* gV = vbase + (long)r_ * L_SZ + gj_;   // +64 per tile
    char* dK0 = (char*)(&lK[0][0]) + tid * 16;
    char* dK1 = (char*)(&lK[1][0]) + tid * 16;
    char* dV0 = (char*)(&lV[0][0]) + tid * 16;
    char* dV1 = (char*)(&lV[1][0]) + tid * 16;
    gload16(dK0, gK);
    gload16(dV0, gV);

    const bf16* qp = q + ((long)bh * N_SZ + qc * 256 + wv * 32 + q32) * 64 + hi * 8;
    short8 qf[4];
#pragma unroll
    for (int t = 0; t < 4; ++t) qf[t] = *(const short8*)(qp + t * 16);

    float mrun = 0.f, lrun = 0.f;
    f32x16 oa0, oa1;
#pragma unroll
    for (int i = 0; i < 16; ++i) { oa0[i] = 0.f; oa1[i] = 0.f; }

    __syncthreads();

    const float CL = 0.18033688011112042f;  // SCALE * log2(e)

    for (int kb = 0; kb < 16; ++kb) {
        const char* curK = (const char*)(&lK[kb & 1][0]);
        const char* curV = (const char*)(&lV[kb & 1][0]);
        if (kb < 15) {
            gload16((kb & 1) ? dK0 : dK1, gK + (kb + 1) * 4096);
            gload16((kb & 1) ? dV0 : dV1, gV + (kb + 1) * 64);
        }

        // S^T: two independent chains (k rows 0-31 and 32-63)
        f32x16 sA, sB;
#pragma unroll
        for (int i = 0; i < 16; ++i) { sA[i] = 0.f; sB[i] = 0.f; }
#pragma unroll
        for (int t = 0; t < 4; ++t) {
            int sl = ((t * 2 + hi) ^ (q32 & 7)) * 16;
            short8 kfA = *(const short8*)(curK + q32 * 128 + sl);
            short8 kfB = *(const short8*)(curK + (32 + q32) * 128 + sl);
            sA = __builtin_amdgcn_mfma_f32_32x32x16_bf16(kfA, qf[t], sA, 0, 0, 0);
            sB = __builtin_amdgcn_mfma_f32_32x32x16_bf16(kfB, qf[t], sB, 0, 0, 0);
        }

        // mask bias: sA reg i -> k_local = (i&3) + 8*(i>>2) + 4*hi; sB: +32
        const float* mf = lMf + kb * 64 + hi * 4;
        float4 ma0 = *(const float4*)(mf);
        float4 ma1 = *(const float4*)(mf + 8);
        float4 ma2 = *(const float4*)(mf + 16);
        float4 ma3 = *(const float4*)(mf + 24);
        float4 mb0 = *(const float4*)(mf + 32);
        float4 mb1 = *(const float4*)(mf + 40);
        float4 mb2 = *(const float4*)(mf + 48);
        float4 mb3 = *(const float4*)(mf + 56);
        float mba[16] = {ma0.x, ma0.y, ma0.z, ma0.w, ma1.x, ma1.y, ma1.z, ma1.w,
                         ma2.x, ma2.y, ma2.z, ma2.w, ma3.x, ma3.y, ma3.z, ma3.w};
        float mbb[16] = {mb0.x, mb0.y, mb0.z, mb0.w, mb1.x, mb1.y, mb1.z, mb1.w,
                         mb2.x, mb2.y, mb2.z, mb2.w, mb3.x, mb3.y, mb3.z, mb3.w};

        float t32[32];
#pragma unroll
        for (int i = 0; i < 16; ++i) {
            t32[i] = fmaf(sA[i], CL, mba[i]);
            t32[16 + i] = fmaf(sB[i], CL, mbb[i]);
        }

        // tile max over 64 k
        float m16[16];
#pragma unroll
        for (int i = 0; i < 16; ++i) m16[i] = fmaxf(t32[i], t32[16 + i]);
        float m8[8];
#pragma unroll
        for (int i = 0; i < 8; ++i) m8[i] = fmaxf(m16[i], m16[i + 8]);
        float tm = fmaxf(fmaxf(fmaxf(m8[0], m8[4]), fmaxf(m8[1], m8[5])),
                         fmaxf(fmaxf(m8[2], m8[6]), fmaxf(m8[3], m8[7])));
        tm = fmaxf(tm, __shfl_xor(tm, 32));

        // defer-max (T13)
        if (__any(tm > mrun + 8.f)) {
            float mnew = fmaxf(mrun, tm);
            float al = fexp2(mrun - mnew);
            mrun = mnew;
            lrun *= al;
#pragma unroll
            for (int i = 0; i < 16; ++i) { oa0[i] *= al; oa1[i] *= al; }
        }

#pragma unroll
        for (int i = 0; i < 32; ++i) t32[i] = fexp2(t32[i] - mrun);
        float s16[16];
#pragma unroll
        for (int i = 0; i < 16; ++i) s16[i] = t32[i] + t32[16 + i];
        float s8[8];
#pragma unroll
        for (int i = 0; i < 8; ++i) s8[i] = s16[i] + s16[i + 8];
        float ps = ((s8[0] + s8[4]) + (s8[1] + s8[5])) + ((s8[2] + s8[6]) + (s8[3] + s8[7]));
        ps += __shfl_xor(ps, 32);
        lrun += ps;

        // P -> 4 bf16 B-fragments (k 0-15,16-31,32-47,48-63) via cvt_pk + permlane32_swap
        union U { unsigned int u[4]; short8 s8v; };
        U fr[4];
#pragma unroll
        for (int fkt = 0; fkt < 4; ++fkt) {
            const float* tp = t32 + fkt * 8;
            unsigned int y0 = cvtpk(tp[0], tp[1]);
            unsigned int y1 = cvtpk(tp[2], tp[3]);
            unsigned int y2 = cvtpk(tp[4], tp[5]);
            unsigned int y3 = cvtpk(tp[6], tp[7]);
            asm("v_permlane32_swap_b32 %0, %1" : "+v"(y0), "+v"(y2));
            asm("v_permlane32_swap_b32 %0, %1" : "+v"(y1), "+v"(y3));
            fr[fkt].u[0] = y0; fr[fkt].u[1] = y1; fr[fkt].u[2] = y2; fr[fkt].u[3] = y3;
        }

        // O^T += V^T . P^T  (2 c-tiles x 4 k-quarters)
#pragma unroll
        for (int kt = 0; kt < 4; ++kt) {
            int sw = ((kt * 2 + hi) ^ (q32 & 7)) * 16;
            short8 v0 = *(const short8*)(curV + q32 * 128 + sw);
            short8 v1 = *(const short8*)(curV + (32 + q32) * 128 + sw);
            oa0 = __builtin_amdgcn_mfma_f32_32x32x16_bf16(v0, fr[kt].s8v, oa0, 0, 0, 0);
            oa1 = __builtin_amdgcn_mfma_f32_32x32x16_bf16(v1, fr[kt].s8v, oa1, 0, 0, 0);
        }

        __syncthreads();
    }

    // epilogue: O^T[c][q] -> o[b][q][h*64 + c]
    float inv = 1.f / lrun;
    bf16* op = o + ((long)b * N_SZ + qc * 256 + wv * 32 + q32) * 512 + h * 64;
#pragma unroll
    for (int ct = 0; ct < 2; ++ct) {
#pragma unroll
        for (int rq = 0; rq < 4; ++rq) {
            int c0 = ct * 32 + rq * 8 + hi * 4;
            float v0 = (ct ? oa1[rq * 4 + 0] : oa0[rq * 4 + 0]) * inv;
            float v1 = (ct ? oa1[rq * 4 + 1] : oa0[rq * 4 + 1]) * inv;
            float v2 = (ct ? oa1[rq * 4 + 2] : oa0[rq * 4 + 2]) * inv;
            float v3 = (ct ? oa1[rq * 4 + 3] : oa0[rq * 4 + 3]) * inv;
            uint2 st;
            st.x = cvtpk(v0, v1);
            st.y = cvtpk(v2, v3);
            *(uint2*)(op + c0) = st;
        }
    }
}

extern "C" void kernel_launch(void* const* d_in, const int* in_sizes, int n_in,
                              void* d_out, int out_size, void* d_ws, size_t ws_size,
                              hipStream_t stream) {
    const float* x_q  = (const float*)d_in[0];
    const float* x_kv = (const float*)d_in[1];
    const int*   mask = (const int*)d_in[2];
    const float* Wq   = (const float*)d_in[3];
    const float* Wk   = (const float*)d_in[4];
    const float* Wv   = (const float*)d_in[5];
    const float* Wo   = (const float*)d_in[6];
    const float* bo   = (const float*)d_in[7];
    const float* rpb  = (const float*)d_in[8];
    float* out = (float*)d_out;

    char* w = (char*)d_ws;
    bf16* xq_bf  = (bf16*)(w + 0);           // reused as o_bf after attention
    bf16* xkv_bf = (bf16*)(w + 16777216);
    bf16* WqT    = (bf16*)(w + 50331648);
    bf16* WkT    = WqT + 262144;
    bf16* WvT    = WkT + 262144;
    bf16* WoT    = WvT + 262144;
    bf16* qh     = (bf16*)(w + 52428800);    // [b][h][n][c]
    bf16* kh     = (bf16*)(w + 69206016);    // [b][h][l][c]
    bf16* vTh    = (bf16*)(w + 102760448);   // [b][h][c][l]
    bf16* o_bf   = xq_bf;

    cvt_all<<<24576, 256, 0, stream>>>(x_q, x_kv, xq_bf, xkv_bf);
    tpose4<<<dim3(16, 16, 4), dim3(32, 8), 0, stream>>>(Wq, Wk, Wv, Wo, WqT, WkT, WvT, WoT);

    gemm_qkv<<<2560, 256, 0, stream>>>(xq_bf, xkv_bf, WqT, WkT, WvT, rpb, qh, kh, vTh);

    attn256<<<512, 512, 0, stream>>>(qh, kh, vTh, mask, o_bf);

    gemm_o<<<dim3(128, 4), 256, 0, stream>>>(o_bf, WoT, out, bo);
}

// Round 6
// 177.122 us; speedup vs baseline: 1.5382x; 1.0430x over previous
//
#include <hip/hip_runtime.h>
#include <hip/hip_bf16.h>

typedef __hip_bfloat16 bf16;
typedef __attribute__((ext_vector_type(8))) short short8;
typedef __attribute__((ext_vector_type(4))) float f32x4;
typedef __attribute__((ext_vector_type(16))) float f32x16;

#define B_SZ 32
#define N_SZ 512
#define L_SZ 1024
#define D_SZ 512
#define H_SZ 8

__device__ __forceinline__ void gload16(void* lds, const void* g) {
    typedef const __attribute__((address_space(1))) unsigned int* gp_t;
    typedef __attribute__((address_space(3))) unsigned int* lp_t;
    __builtin_amdgcn_global_load_lds((gp_t)g, (lp_t)lds, 16, 0, 0);
}

__device__ __forceinline__ unsigned int cvtpk(float lo, float hi) {
    unsigned int r;
    asm("v_cvt_pk_bf16_f32 %0, %1, %2" : "=v"(r) : "v"(lo), "v"(hi));
    return r;
}

__device__ __forceinline__ float fexp2(float x) {
    float r;
    asm("v_exp_f32 %0, %1" : "=v"(r) : "v"(x));
    return r;
}

// ---------------- f32 -> bf16 convert (both inputs, one dispatch) ----------------
struct alignas(8) B4 { bf16 a, b, c, d; };

__global__ void cvt_all(const float* __restrict__ xq, const float* __restrict__ xkv,
                        bf16* __restrict__ dq, bf16* __restrict__ dkv) {
    int i = blockIdx.x * 256 + threadIdx.x;
    const float* s;
    bf16* d;
    if (i < 2097152) {
        s = xq; d = dq;
    } else {
        i -= 2097152; s = xkv; d = dkv;
    }
    float4 v = ((const float4*)s)[i];
    B4 o;
    o.a = __float2bfloat16(v.x);
    o.b = __float2bfloat16(v.y);
    o.c = __float2bfloat16(v.z);
    o.d = __float2bfloat16(v.w);
    *(B4*)(d + (size_t)i * 4) = o;
}

// ---------------- 512x512 transpose + convert: Wt[e][d] = bf16(W[d][e]) ----------------
__global__ void tpose4(const float* __restrict__ s0, const float* __restrict__ s1,
                       const float* __restrict__ s2, const float* __restrict__ s3,
                       bf16* __restrict__ d0, bf16* __restrict__ d1,
                       bf16* __restrict__ d2, bf16* __restrict__ d3) {
    __shared__ float t[32][33];
    const float* s = blockIdx.z == 0 ? s0 : blockIdx.z == 1 ? s1 : blockIdx.z == 2 ? s2 : s3;
    bf16* d = blockIdx.z == 0 ? d0 : blockIdx.z == 1 ? d1 : blockIdx.z == 2 ? d2 : d3;
    int tx = threadIdx.x, ty = threadIdx.y;  // 32 x 8
    int r0 = blockIdx.y * 32, c0 = blockIdx.x * 32;
#pragma unroll
    for (int i = 0; i < 32; i += 8)
        t[ty + i][tx] = s[(size_t)(r0 + ty + i) * 512 + c0 + tx];
    __syncthreads();
#pragma unroll
    for (int i = 0; i < 32; i += 8)
        d[(size_t)(c0 + ty + i) * 512 + r0 + tx] = __float2bfloat16(t[tx][ty + i]);
}

// ---------------- fused QKV projection: 2560 blocks, dbuf pipeline ----------------
// mode 0: Q = xq * WqT^T -> qh [b][h][n][c]
// mode 1: K = xkv * WkT^T + rpb -> kh [b][h][l][c]
// mode 2: V^T = WvT * xkv^T -> vTh [b][h][c][l]
__global__ __launch_bounds__(256) void gemm_qkv(
    const bf16* __restrict__ xq, const bf16* __restrict__ xkv,
    const bf16* __restrict__ WqT, const bf16* __restrict__ WkT,
    const bf16* __restrict__ WvT, const float* __restrict__ rpb,
    bf16* __restrict__ qh, bf16* __restrict__ kh, bf16* __restrict__ vTh) {
    __shared__ char sm[2][32768];  // [buf][A 16KB | B 16KB]
    const int tid = threadIdx.x;
    const int wave = tid >> 6, lane = tid & 63;
    const int wr = wave >> 1, wc = wave & 1;
    const int g16 = lane >> 4, r16 = lane & 15;

    // bijective XCD swizzle: 2560 = 8 * 320, each XCD gets a contiguous slab,
    // col-index stays innermost within the slab -> A-tile L2 reuse
    const int orig = blockIdx.x;
    const int bid = (orig & 7) * 320 + (orig >> 3);

    int mode;
    long rowBase;
    int colBase;
    const bf16 *A, *Bt;
    if (bid < 512) {
        mode = 0; A = xq; Bt = WqT;
        rowBase = (long)(bid >> 2) * 128; colBase = (bid & 3) * 128;
    } else if (bid < 1536) {
        mode = 1; int t = bid - 512; A = xkv; Bt = WkT;
        rowBase = (long)(t >> 2) * 128; colBase = (t & 3) * 128;
    } else {
        mode = 2; int t = bid - 1536; A = WvT; Bt = xkv;
        rowBase = (long)(t & 3) * 128; colBase = (t >> 2) * 128;
    }

    // loop-invariant staging addresses (pre-swizzled source, linear LDS dest)
    const int row_ = tid >> 3;                       // 0..31 (rnd adds 32 rows)
    const int gj_ = ((tid & 7) ^ (row_ & 7)) * 8;    // row_&7 invariant across rnd
    const bf16* aSrc = A + (rowBase + row_) * 512 + gj_;
    const bf16* bSrc = Bt + ((long)colBase + row_) * 512 + gj_;

    f32x4 acc[4][4];
#pragma unroll
    for (int m = 0; m < 4; ++m)
#pragma unroll
        for (int n = 0; n < 4; ++n) acc[m][n] = {0.f, 0.f, 0.f, 0.f};

    // prologue: stage K-tile 0 into buf 0
#pragma unroll
    for (int rnd = 0; rnd < 4; ++rnd) {
        gload16(&sm[0][rnd * 4096 + tid * 16], aSrc + rnd * 16384);
        gload16(&sm[0][16384 + rnd * 4096 + tid * 16], bSrc + rnd * 16384);
    }
    __syncthreads();  // implicit vmcnt(0): buf0 staged

    for (int t = 0; t < 8; ++t) {
        const int cur = t & 1;
        if (t < 7) {
            const int nk = (t + 1) * 64;
#pragma unroll
            for (int rnd = 0; rnd < 4; ++rnd) {
                gload16(&sm[cur ^ 1][rnd * 4096 + tid * 16], aSrc + rnd * 16384 + nk);
                gload16(&sm[cur ^ 1][16384 + rnd * 4096 + tid * 16], bSrc + rnd * 16384 + nk);
            }
        }
        const char* lA = &sm[cur][0];
        const char* lB = &sm[cur][16384];
#pragma unroll
        for (int kk = 0; kk < 2; ++kk) {
            short8 a[4], b[4];
#pragma unroll
            for (int m = 0; m < 4; ++m) {
                int row = wr * 64 + m * 16 + r16;
                a[m] = *(const short8*)(lA + row * 128 + (((kk * 4 + g16) ^ (row & 7)) * 16));
            }
#pragma unroll
            for (int n = 0; n < 4; ++n) {
                int row = wc * 64 + n * 16 + r16;
                b[n] = *(const short8*)(lB + row * 128 + (((kk * 4 + g16) ^ (row & 7)) * 16));
            }
#pragma unroll
            for (int m = 0; m < 4; ++m)
#pragma unroll
                for (int n = 0; n < 4; ++n)
                    acc[m][n] =
                        __builtin_amdgcn_mfma_f32_16x16x32_bf16(a[m], b[n], acc[m][n], 0, 0, 0);
        }
        __syncthreads();  // drains vmcnt(0): next buf staged; all reads of cur done
    }

#pragma unroll
    for (int m = 0; m < 4; ++m) {
#pragma unroll
        for (int r = 0; r < 4; ++r) {
            long gm = rowBase + wr * 64 + m * 16 + g16 * 4 + r;
            if (mode == 2) {
                int e = (int)gm;
                int hh = e >> 6, c = e & 63;
#pragma unroll
                for (int n = 0; n < 4; ++n) {
                    int gl = colBase + wc * 64 + n * 16 + r16;
                    int bb = gl >> 10, s = gl & 1023;
                    vTh[(((long)bb * H_SZ + hh) * 64 + c) * (long)L_SZ + s] =
                        __float2bfloat16(acc[m][n][r]);
                }
            } else if (mode == 1) {
                int bb = (int)(gm >> 10), s = (int)gm & 1023;
#pragma unroll
                for (int n = 0; n < 4; ++n) {
                    int e = colBase + wc * 64 + n * 16 + r16;
                    float v = acc[m][n][r] + rpb[(long)s * 512 + e];
                    int hh = e >> 6, c = e & 63;
                    kh[(((long)bb * H_SZ + hh) * (long)L_SZ + s) * 64 + c] = __float2bfloat16(v);
                }
            } else {
                int bb = (int)(gm >> 9), s = (int)gm & 511;
#pragma unroll
                for (int n = 0; n < 4; ++n) {
                    int e = colBase + wc * 64 + n * 16 + r16;
                    int hh = e >> 6, c = e & 63;
                    qh[(((long)bb * H_SZ + hh) * (long)N_SZ + s) * 64 + c] =
                        __float2bfloat16(acc[m][n][r]);
                }
            }
        }
    }
}

// ---------------- O projection: dbuf pipeline, f32 out + bo ----------------
__global__ __launch_bounds__(256) void gemm_o(const bf16* __restrict__ A,
                                              const bf16* __restrict__ Bt,
                                              float* __restrict__ outp,
                                              const float* __restrict__ bias) {
    __shared__ char sm[2][32768];
    const int tid = threadIdx.x;
    const int wave = tid >> 6, lane = tid & 63;
    const int wr = wave >> 1, wc = wave & 1;
    const int g16 = lane >> 4, r16 = lane & 15;

    const int orig = blockIdx.x;                 // 512 = 8 * 64
    const int bid = (orig & 7) * 64 + (orig >> 3);
    const long rowBase = (long)(bid >> 2) * 128;
    const int colBase = (bid & 3) * 128;

    const int row_ = tid >> 3;
    const int gj_ = ((tid & 7) ^ (row_ & 7)) * 8;
    const bf16* aSrc = A + (rowBase + row_) * 512 + gj_;
    const bf16* bSrc = Bt + ((long)colBase + row_) * 512 + gj_;

    f32x4 acc[4][4];
#pragma unroll
    for (int m = 0; m < 4; ++m)
#pragma unroll
        for (int n = 0; n < 4; ++n) acc[m][n] = {0.f, 0.f, 0.f, 0.f};

#pragma unroll
    for (int rnd = 0; rnd < 4; ++rnd) {
        gload16(&sm[0][rnd * 4096 + tid * 16], aSrc + rnd * 16384);
        gload16(&sm[0][16384 + rnd * 4096 + tid * 16], bSrc + rnd * 16384);
    }
    __syncthreads();

    for (int t = 0; t < 8; ++t) {
        const int cur = t & 1;
        if (t < 7) {
            const int nk = (t + 1) * 64;
#pragma unroll
            for (int rnd = 0; rnd < 4; ++rnd) {
                gload16(&sm[cur ^ 1][rnd * 4096 + tid * 16], aSrc + rnd * 16384 + nk);
                gload16(&sm[cur ^ 1][16384 + rnd * 4096 + tid * 16], bSrc + rnd * 16384 + nk);
            }
        }
        const char* lA = &sm[cur][0];
        const char* lB = &sm[cur][16384];
#pragma unroll
        for (int kk = 0; kk < 2; ++kk) {
            short8 a[4], b[4];
#pragma unroll
            for (int m = 0; m < 4; ++m) {
                int row = wr * 64 + m * 16 + r16;
                a[m] = *(const short8*)(lA + row * 128 + (((kk * 4 + g16) ^ (row & 7)) * 16));
            }
#pragma unroll
            for (int n = 0; n < 4; ++n) {
                int row = wc * 64 + n * 16 + r16;
                b[n] = *(const short8*)(lB + row * 128 + (((kk * 4 + g16) ^ (row & 7)) * 16));
            }
#pragma unroll
            for (int m = 0; m < 4; ++m)
#pragma unroll
                for (int n = 0; n < 4; ++n)
                    acc[m][n] =
                        __builtin_amdgcn_mfma_f32_16x16x32_bf16(a[m], b[n], acc[m][n], 0, 0, 0);
        }
        __syncthreads();
    }

#pragma unroll
    for (int m = 0; m < 4; ++m) {
#pragma unroll
        for (int r = 0; r < 4; ++r) {
            long gm = rowBase + wr * 64 + m * 16 + g16 * 4 + r;
#pragma unroll
            for (int n = 0; n < 4; ++n) {
                int e = colBase + wc * 64 + n * 16 + r16;
                outp[gm * 512 + e] = acc[m][n][r] + bias[e];
            }
        }
    }
}

// ---------------- flash attention: KVBLK=64, swapped QK^T, in-register softmax ----
__global__ __launch_bounds__(512, 4) void attn256(const bf16* __restrict__ q,
                                                  const bf16* __restrict__ k,
                                                  const bf16* __restrict__ vT,
                                                  const int* __restrict__ mask,
                                                  bf16* __restrict__ o) {
    __shared__ bf16 lK[2][64 * 64];   // [k 64][c 64], row slots xor-swizzled by (k&7)
    __shared__ bf16 lV[2][64 * 64];   // [c 64][k 64], row slots xor-swizzled by (c&7)
    __shared__ float lMf[1024];       // mask -> {0, -1e38}

    const int tid = threadIdx.x;
    const int wv = tid >> 6, lane = tid & 63;
    const int q32 = lane & 31, hi = lane >> 5;

    const int wg = blockIdx.x;
    const int xcd = wg & 7, slot = wg >> 3;
    const int bh = xcd * 32 + (slot >> 1), qc = slot & 1;
    const int b = bh >> 3, h = bh & 7;

    const bf16* kbase = k + (long)bh * L_SZ * 64;
    const bf16* vbase = vT + (long)bh * 64 * L_SZ;

    const int* mrow = mask + b * L_SZ;
    lMf[tid] = mrow[tid] ? -1e38f : 0.f;
    lMf[tid + 512] = mrow[tid + 512] ? -1e38f : 0.f;

    const int r_ = tid >> 3, j_ = tid & 7;
    const int gj_ = (j_ ^ (r_ & 7)) * 8;
    const bf16* gK = kbase + r_ * 64 + gj_;           // +4096 per tile
    const bf16* gV = vbase + (long)r_ * L_SZ + gj_;   // +64 per tile
    char* dK0 = (char*)(&lK[0][0]) + tid * 16;
    char* dK1 = (char*)(&lK[1][0]) + tid * 16;
    char* dV0 = (char*)(&lV[0][0]) + tid * 16;
    char* dV1 = (char*)(&lV[1][0]) + tid * 16;
    gload16(dK0, gK);
    gload16(dV0, gV);

    const bf16* qp = q + ((long)bh * N_SZ + qc * 256 + wv * 32 + q32) * 64 + hi * 8;
    short8 qf[4];
#pragma unroll
    for (int t = 0; t < 4; ++t) qf[t] = *(const short8*)(qp + t * 16);

    float mrun = 0.f, lrun = 0.f;
    f32x16 oa0, oa1;
#pragma unroll
    for (int i = 0; i < 16; ++i) { oa0[i] = 0.f; oa1[i] = 0.f; }

    __syncthreads();

    const float CL = 0.18033688011112042f;  // SCALE * log2(e)

    for (int kb = 0; kb < 16; ++kb) {
        const char* curK = (const char*)(&lK[kb & 1][0]);
        const char* curV = (const char*)(&lV[kb & 1][0]);
        if (kb < 15) {
            gload16((kb & 1) ? dK0 : dK1, gK + (kb + 1) * 4096);
            gload16((kb & 1) ? dV0 : dV1, gV + (kb + 1) * 64);
        }

        // S^T: two independent chains (k rows 0-31 and 32-63)
        f32x16 sA, sB;
#pragma unroll
        for (int i = 0; i < 16; ++i) { sA[i] = 0.f; sB[i] = 0.f; }
#pragma unroll
        for (int t = 0; t < 4; ++t) {
            int sl = ((t * 2 + hi) ^ (q32 & 7)) * 16;
            short8 kfA = *(const short8*)(curK + q32 * 128 + sl);
            short8 kfB = *(const short8*)(curK + (32 + q32) * 128 + sl);
            sA = __builtin_amdgcn_mfma_f32_32x32x16_bf16(kfA, qf[t], sA, 0, 0, 0);
            sB = __builtin_amdgcn_mfma_f32_32x32x16_bf16(kfB, qf[t], sB, 0, 0, 0);
        }

        // mask bias: sA reg i -> k_local = (i&3) + 8*(i>>2) + 4*hi; sB: +32
        const float* mf = lMf + kb * 64 + hi * 4;
        float4 ma0 = *(const float4*)(mf);
        float4 ma1 = *(const float4*)(mf + 8);
        float4 ma2 = *(const float4*)(mf + 16);
        float4 ma3 = *(const float4*)(mf + 24);
        float4 mb0 = *(const float4*)(mf + 32);
        float4 mb1 = *(const float4*)(mf + 40);
        float4 mb2 = *(const float4*)(mf + 48);
        float4 mb3 = *(const float4*)(mf + 56);
        float mba[16] = {ma0.x, ma0.y, ma0.z, ma0.w, ma1.x, ma1.y, ma1.z, ma1.w,
                         ma2.x, ma2.y, ma2.z, ma2.w, ma3.x, ma3.y, ma3.z, ma3.w};
        float mbb[16] = {mb0.x, mb0.y, mb0.z, mb0.w, mb1.x, mb1.y, mb1.z, mb1.w,
                         mb2.x, mb2.y, mb2.z, mb2.w, mb3.x, mb3.y, mb3.z, mb3.w};

        float t32[32];
#pragma unroll
        for (int i = 0; i < 16; ++i) {
            t32[i] = fmaf(sA[i], CL, mba[i]);
            t32[16 + i] = fmaf(sB[i], CL, mbb[i]);
        }

        // tile max over 64 k
        float m16[16];
#pragma unroll
        for (int i = 0; i < 16; ++i) m16[i] = fmaxf(t32[i], t32[16 + i]);
        float m8[8];
#pragma unroll
        for (int i = 0; i < 8; ++i) m8[i] = fmaxf(m16[i], m16[i + 8]);
        float tm = fmaxf(fmaxf(fmaxf(m8[0], m8[4]), fmaxf(m8[1], m8[5])),
                         fmaxf(fmaxf(m8[2], m8[6]), fmaxf(m8[3], m8[7])));
        tm = fmaxf(tm, __shfl_xor(tm, 32));

        // defer-max (T13)
        if (__any(tm > mrun + 8.f)) {
            float mnew = fmaxf(mrun, tm);
            float al = fexp2(mrun - mnew);
            mrun = mnew;
            lrun *= al;
#pragma unroll
            for (int i = 0; i < 16; ++i) { oa0[i] *= al; oa1[i] *= al; }
        }

#pragma unroll
        for (int i = 0; i < 32; ++i) t32[i] = fexp2(t32[i] - mrun);
        float s16[16];
#pragma unroll
        for (int i = 0; i < 16; ++i) s16[i] = t32[i] + t32[16 + i];
        float s8[8];
#pragma unroll
        for (int i = 0; i < 8; ++i) s8[i] = s16[i] + s16[i + 8];
        float ps = ((s8[0] + s8[4]) + (s8[1] + s8[5])) + ((s8[2] + s8[6]) + (s8[3] + s8[7]));
        ps += __shfl_xor(ps, 32);
        lrun += ps;

        // P -> 4 bf16 B-fragments (k 0-15,16-31,32-47,48-63) via cvt_pk + permlane32_swap
        union U { unsigned int u[4]; short8 s8v; };
        U fr[4];
#pragma unroll
        for (int fkt = 0; fkt < 4; ++fkt) {
            const float* tp = t32 + fkt * 8;
            unsigned int y0 = cvtpk(tp[0], tp[1]);
            unsigned int y1 = cvtpk(tp[2], tp[3]);
            unsigned int y2 = cvtpk(tp[4], tp[5]);
            unsigned int y3 = cvtpk(tp[6], tp[7]);
            asm("v_permlane32_swap_b32 %0, %1" : "+v"(y0), "+v"(y2));
            asm("v_permlane32_swap_b32 %0, %1" : "+v"(y1), "+v"(y3));
            fr[fkt].u[0] = y0; fr[fkt].u[1] = y1; fr[fkt].u[2] = y2; fr[fkt].u[3] = y3;
        }

        // O^T += V^T . P^T  (2 c-tiles x 4 k-quarters)
#pragma unroll
        for (int kt = 0; kt < 4; ++kt) {
            int sw = ((kt * 2 + hi) ^ (q32 & 7)) * 16;
            short8 v0 = *(const short8*)(curV + q32 * 128 + sw);
            short8 v1 = *(const short8*)(curV + (32 + q32) * 128 + sw);
            oa0 = __builtin_amdgcn_mfma_f32_32x32x16_bf16(v0, fr[kt].s8v, oa0, 0, 0, 0);
            oa1 = __builtin_amdgcn_mfma_f32_32x32x16_bf16(v1, fr[kt].s8v, oa1, 0, 0, 0);
        }

        __syncthreads();
    }

    // epilogue: O^T[c][q] -> o[b][q][h*64 + c]
    float inv = 1.f / lrun;
    bf16* op = o + ((long)b * N_SZ + qc * 256 + wv * 32 + q32) * 512 + h * 64;
#pragma unroll
    for (int ct = 0; ct < 2; ++ct) {
#pragma unroll
        for (int rq = 0; rq < 4; ++rq) {
            int c0 = ct * 32 + rq * 8 + hi * 4;
            float v0 = (ct ? oa1[rq * 4 + 0] : oa0[rq * 4 + 0]) * inv;
            float v1 = (ct ? oa1[rq * 4 + 1] : oa0[rq * 4 + 1]) * inv;
            float v2 = (ct ? oa1[rq * 4 + 2] : oa0[rq * 4 + 2]) * inv;
            float v3 = (ct ? oa1[rq * 4 + 3] : oa0[rq * 4 + 3]) * inv;
            uint2 st;
            st.x = cvtpk(v0, v1);
            st.y = cvtpk(v2, v3);
            *(uint2*)(op + c0) = st;
        }
    }
}

extern "C" void kernel_launch(void* const* d_in, const int* in_sizes, int n_in,
                              void* d_out, int out_size, void* d_ws, size_t ws_size,
                              hipStream_t stream) {
    const float* x_q  = (const float*)d_in[0];
    const float* x_kv = (const float*)d_in[1];
    const int*   mask = (const int*)d_in[2];
    const float* Wq   = (const float*)d_in[3];
    const float* Wk   = (const float*)d_in[4];
    const float* Wv   = (const float*)d_in[5];
    const float* Wo   = (const float*)d_in[6];
    const float* bo   = (const float*)d_in[7];
    const float* rpb  = (const float*)d_in[8];
    float* out = (float*)d_out;

    char* w = (char*)d_ws;
    bf16* xq_bf  = (bf16*)(w + 0);           // reused as o_bf after attention
    bf16* xkv_bf = (bf16*)(w + 16777216);
    bf16* WqT    = (bf16*)(w + 50331648);
    bf16* WkT    = WqT + 262144;
    bf16* WvT    = WkT + 262144;
    bf16* WoT    = WvT + 262144;
    bf16* qh     = (bf16*)(w + 52428800);    // [b][h][n][c]
    bf16* kh     = (bf16*)(w + 69206016);    // [b][h][l][c]
    bf16* vTh    = (bf16*)(w + 102760448);   // [b][h][c][l]
    bf16* o_bf   = xq_bf;

    cvt_all<<<24576, 256, 0, stream>>>(x_q, x_kv, xq_bf, xkv_bf);
    tpose4<<<dim3(16, 16, 4), dim3(32, 8), 0, stream>>>(Wq, Wk, Wv, Wo, WqT, WkT, WvT, WoT);

    gemm_qkv<<<2560, 256, 0, stream>>>(xq_bf, xkv_bf, WqT, WkT, WvT, rpb, qh, kh, vTh);

    attn256<<<512, 512, 0, stream>>>(qh, kh, vTh, mask, o_bf);

    gemm_o<<<512, 256, 0, stream>>>(o_bf, WoT, out, bo);
}

// Round 7
// 164.374 us; speedup vs baseline: 1.6575x; 1.0776x over previous
//
#include <hip/hip_runtime.h>
#include <hip/hip_bf16.h>

typedef __hip_bfloat16 bf16;
typedef __attribute__((ext_vector_type(8))) short short8;
typedef __attribute__((ext_vector_type(4))) float f32x4;
typedef __attribute__((ext_vector_type(16))) float f32x16;

#define B_SZ 32
#define N_SZ 512
#define L_SZ 1024
#define D_SZ 512
#define H_SZ 8

__device__ __forceinline__ void gload16(void* lds, const void* g) {
    typedef const __attribute__((address_space(1))) unsigned int* gp_t;
    typedef __attribute__((address_space(3))) unsigned int* lp_t;
    __builtin_amdgcn_global_load_lds((gp_t)g, (lp_t)lds, 16, 0, 0);
}

__device__ __forceinline__ unsigned int cvtpk(float lo, float hi) {
    unsigned int r;
    asm("v_cvt_pk_bf16_f32 %0, %1, %2" : "=v"(r) : "v"(lo), "v"(hi));
    return r;
}

__device__ __forceinline__ float fexp2(float x) {
    float r;
    asm("v_exp_f32 %0, %1" : "=v"(r) : "v"(x));
    return r;
}

// ---------------- f32 -> bf16 convert (both inputs, one dispatch) ----------------
struct alignas(8) B4 { bf16 a, b, c, d; };

__global__ void cvt_all(const float* __restrict__ xq, const float* __restrict__ xkv,
                        bf16* __restrict__ dq, bf16* __restrict__ dkv) {
    int i = blockIdx.x * 256 + threadIdx.x;
    const float* s;
    bf16* d;
    if (i < 2097152) {
        s = xq; d = dq;
    } else {
        i -= 2097152; s = xkv; d = dkv;
    }
    float4 v = ((const float4*)s)[i];
    B4 o;
    o.a = __float2bfloat16(v.x);
    o.b = __float2bfloat16(v.y);
    o.c = __float2bfloat16(v.z);
    o.d = __float2bfloat16(v.w);
    *(B4*)(d + (size_t)i * 4) = o;
}

// ---------------- 512x512 transpose + convert: Wt[e][d] = bf16(W[d][e]) ----------------
__global__ void tpose4(const float* __restrict__ s0, const float* __restrict__ s1,
                       const float* __restrict__ s2, const float* __restrict__ s3,
                       bf16* __restrict__ d0, bf16* __restrict__ d1,
                       bf16* __restrict__ d2, bf16* __restrict__ d3) {
    __shared__ float t[32][33];
    const float* s = blockIdx.z == 0 ? s0 : blockIdx.z == 1 ? s1 : blockIdx.z == 2 ? s2 : s3;
    bf16* d = blockIdx.z == 0 ? d0 : blockIdx.z == 1 ? d1 : blockIdx.z == 2 ? d2 : d3;
    int tx = threadIdx.x, ty = threadIdx.y;  // 32 x 8
    int r0 = blockIdx.y * 32, c0 = blockIdx.x * 32;
#pragma unroll
    for (int i = 0; i < 32; i += 8)
        t[ty + i][tx] = s[(size_t)(r0 + ty + i) * 512 + c0 + tx];
    __syncthreads();
#pragma unroll
    for (int i = 0; i < 32; i += 8)
        d[(size_t)(c0 + ty + i) * 512 + r0 + tx] = __float2bfloat16(t[tx][ty + i]);
}

// ---------------- fused QKV projection: 2560 blocks, dbuf pipeline ----------------
// mode 0: Q = xq * WqT^T -> qh [b][h][n][c]
// mode 1: K = xkv * WkT^T + rpb -> kh [b][h][l][c]
// mode 2: V^T = WvT * xkv^T -> vTh [b][h][c][l]
__global__ __launch_bounds__(256) void gemm_qkv(
    const bf16* __restrict__ xq, const bf16* __restrict__ xkv,
    const bf16* __restrict__ WqT, const bf16* __restrict__ WkT,
    const bf16* __restrict__ WvT, const float* __restrict__ rpb,
    bf16* __restrict__ qh, bf16* __restrict__ kh, bf16* __restrict__ vTh) {
    __shared__ char sm[2][32768];  // [buf][A 16KB | B 16KB]; reused by epilogue
    const int tid = threadIdx.x;
    const int wave = tid >> 6, lane = tid & 63;
    const int wr = wave >> 1, wc = wave & 1;
    const int g16 = lane >> 4, r16 = lane & 15;

    // bijective XCD swizzle: 2560 = 8 * 320
    const int orig = blockIdx.x;
    const int bid = (orig & 7) * 320 + (orig >> 3);

    int mode;
    long rowBase;
    int colBase;
    const bf16 *A, *Bt;
    if (bid < 512) {
        mode = 0; A = xq; Bt = WqT;
        rowBase = (long)(bid >> 2) * 128; colBase = (bid & 3) * 128;
    } else if (bid < 1536) {
        mode = 1; int t = bid - 512; A = xkv; Bt = WkT;
        rowBase = (long)(t >> 2) * 128; colBase = (t & 3) * 128;
    } else {
        mode = 2; int t = bid - 1536; A = WvT; Bt = xkv;
        rowBase = (long)(t & 3) * 128; colBase = (t >> 2) * 128;
    }

    // loop-invariant staging addresses (pre-swizzled source, linear LDS dest)
    const int row_ = tid >> 3;
    const int gj_ = ((tid & 7) ^ (row_ & 7)) * 8;
    const bf16* aSrc = A + (rowBase + row_) * 512 + gj_;
    const bf16* bSrc = Bt + ((long)colBase + row_) * 512 + gj_;

    f32x4 acc[4][4];
#pragma unroll
    for (int m = 0; m < 4; ++m)
#pragma unroll
        for (int n = 0; n < 4; ++n) acc[m][n] = {0.f, 0.f, 0.f, 0.f};

    // prologue: stage K-tile 0 into buf 0
#pragma unroll
    for (int rnd = 0; rnd < 4; ++rnd) {
        gload16(&sm[0][rnd * 4096 + tid * 16], aSrc + rnd * 16384);
        gload16(&sm[0][16384 + rnd * 4096 + tid * 16], bSrc + rnd * 16384);
    }
    __syncthreads();

    for (int t = 0; t < 8; ++t) {
        const int cur = t & 1;
        if (t < 7) {
            const int nk = (t + 1) * 64;
#pragma unroll
            for (int rnd = 0; rnd < 4; ++rnd) {
                gload16(&sm[cur ^ 1][rnd * 4096 + tid * 16], aSrc + rnd * 16384 + nk);
                gload16(&sm[cur ^ 1][16384 + rnd * 4096 + tid * 16], bSrc + rnd * 16384 + nk);
            }
        }
        const char* lA = &sm[cur][0];
        const char* lB = &sm[cur][16384];
#pragma unroll
        for (int kk = 0; kk < 2; ++kk) {
            short8 a[4], b[4];
#pragma unroll
            for (int m = 0; m < 4; ++m) {
                int row = wr * 64 + m * 16 + r16;
                a[m] = *(const short8*)(lA + row * 128 + (((kk * 4 + g16) ^ (row & 7)) * 16));
            }
#pragma unroll
            for (int n = 0; n < 4; ++n) {
                int row = wc * 64 + n * 16 + r16;
                b[n] = *(const short8*)(lB + row * 128 + (((kk * 4 + g16) ^ (row & 7)) * 16));
            }
#pragma unroll
            for (int m = 0; m < 4; ++m)
#pragma unroll
                for (int n = 0; n < 4; ++n)
                    acc[m][n] =
                        __builtin_amdgcn_mfma_f32_16x16x32_bf16(a[m], b[n], acc[m][n], 0, 0, 0);
        }
        __syncthreads();
    }

    // ---------- epilogue: stage f32 tile in per-wave LDS, store coalesced 16B ----------
    // wave tile = 64 rows x 64 cols, entirely within one head (row/col bases mult. of 64)
    float* ep = (float*)((char*)sm + wave * 16384);  // 64 x 64 f32 = 16KB
#pragma unroll
    for (int m = 0; m < 4; ++m)
#pragma unroll
        for (int n = 0; n < 4; ++n)
#pragma unroll
            for (int r = 0; r < 4; ++r)
                ep[(m * 16 + g16 * 4 + r) * 64 + n * 16 + r16] = acc[m][n][r];

    const long gm0 = rowBase + wr * 64;  // first row of wave tile (mult. of 64)
    const int e0 = colBase + wc * 64;    // first col (mult. of 64)
    bf16* obase;
    int rstride;
    int s0g = 0;
    if (mode == 2) {
        int hh = (int)gm0 >> 6;
        int bb = e0 >> 10, s0 = e0 & 1023;
        obase = vTh + (((long)bb * H_SZ + hh) * 64 + ((int)gm0 & 63)) * (long)L_SZ + s0;
        rstride = L_SZ;
    } else if (mode == 1) {
        int bb = (int)(gm0 >> 10), s0 = (int)gm0 & 1023;
        int hh = e0 >> 6;
        obase = kh + (((long)bb * H_SZ + hh) * (long)L_SZ + s0) * 64 + (e0 & 63);
        rstride = 64;
        s0g = (int)gm0 & 1023;
    } else {
        int bb = (int)(gm0 >> 9), s0 = (int)gm0 & 511;
        int hh = e0 >> 6;
        obase = qh + (((long)bb * H_SZ + hh) * (long)N_SZ + s0) * 64 + (e0 & 63);
        rstride = 64;
    }

#pragma unroll
    for (int i = 0; i < 8; ++i) {
        int chunk = i * 64 + lane;          // 0..511
        int lr = chunk >> 3, cc = chunk & 7;  // row, 16B-chunk within row
        float4 fa = *(float4*)(ep + lr * 64 + cc * 8);
        float4 fb = *(float4*)(ep + lr * 64 + cc * 8 + 4);
        if (mode == 1) {
            const float* rp = rpb + (long)(s0g + lr) * 512 + e0 + cc * 8;
            float4 ra = *(const float4*)rp;
            float4 rb = *(const float4*)(rp + 4);
            fa.x += ra.x; fa.y += ra.y; fa.z += ra.z; fa.w += ra.w;
            fb.x += rb.x; fb.y += rb.y; fb.z += rb.z; fb.w += rb.w;
        }
        uint4 st;
        st.x = cvtpk(fa.x, fa.y);
        st.y = cvtpk(fa.z, fa.w);
        st.z = cvtpk(fb.x, fb.y);
        st.w = cvtpk(fb.z, fb.w);
        *(uint4*)(obase + (long)lr * rstride + cc * 8) = st;
    }
}

// ---------------- O projection: dbuf pipeline, f32 out + bo ----------------
__global__ __launch_bounds__(256) void gemm_o(const bf16* __restrict__ A,
                                              const bf16* __restrict__ Bt,
                                              float* __restrict__ outp,
                                              const float* __restrict__ bias) {
    __shared__ char sm[2][32768];
    const int tid = threadIdx.x;
    const int wave = tid >> 6, lane = tid & 63;
    const int wr = wave >> 1, wc = wave & 1;
    const int g16 = lane >> 4, r16 = lane & 15;

    const int orig = blockIdx.x;                 // 512 = 8 * 64
    const int bid = (orig & 7) * 64 + (orig >> 3);
    const long rowBase = (long)(bid >> 2) * 128;
    const int colBase = (bid & 3) * 128;

    const int row_ = tid >> 3;
    const int gj_ = ((tid & 7) ^ (row_ & 7)) * 8;
    const bf16* aSrc = A + (rowBase + row_) * 512 + gj_;
    const bf16* bSrc = Bt + ((long)colBase + row_) * 512 + gj_;

    f32x4 acc[4][4];
#pragma unroll
    for (int m = 0; m < 4; ++m)
#pragma unroll
        for (int n = 0; n < 4; ++n) acc[m][n] = {0.f, 0.f, 0.f, 0.f};

#pragma unroll
    for (int rnd = 0; rnd < 4; ++rnd) {
        gload16(&sm[0][rnd * 4096 + tid * 16], aSrc + rnd * 16384);
        gload16(&sm[0][16384 + rnd * 4096 + tid * 16], bSrc + rnd * 16384);
    }
    __syncthreads();

    for (int t = 0; t < 8; ++t) {
        const int cur = t & 1;
        if (t < 7) {
            const int nk = (t + 1) * 64;
#pragma unroll
            for (int rnd = 0; rnd < 4; ++rnd) {
                gload16(&sm[cur ^ 1][rnd * 4096 + tid * 16], aSrc + rnd * 16384 + nk);
                gload16(&sm[cur ^ 1][16384 + rnd * 4096 + tid * 16], bSrc + rnd * 16384 + nk);
            }
        }
        const char* lA = &sm[cur][0];
        const char* lB = &sm[cur][16384];
#pragma unroll
        for (int kk = 0; kk < 2; ++kk) {
            short8 a[4], b[4];
#pragma unroll
            for (int m = 0; m < 4; ++m) {
                int row = wr * 64 + m * 16 + r16;
                a[m] = *(const short8*)(lA + row * 128 + (((kk * 4 + g16) ^ (row & 7)) * 16));
            }
#pragma unroll
            for (int n = 0; n < 4; ++n) {
                int row = wc * 64 + n * 16 + r16;
                b[n] = *(const short8*)(lB + row * 128 + (((kk * 4 + g16) ^ (row & 7)) * 16));
            }
#pragma unroll
            for (int m = 0; m < 4; ++m)
#pragma unroll
                for (int n = 0; n < 4; ++n)
                    acc[m][n] =
                        __builtin_amdgcn_mfma_f32_16x16x32_bf16(a[m], b[n], acc[m][n], 0, 0, 0);
        }
        __syncthreads();
    }

#pragma unroll
    for (int m = 0; m < 4; ++m) {
#pragma unroll
        for (int r = 0; r < 4; ++r) {
            long gm = rowBase + wr * 64 + m * 16 + g16 * 4 + r;
#pragma unroll
            for (int n = 0; n < 4; ++n) {
                int e = colBase + wc * 64 + n * 16 + r16;
                outp[gm * 512 + e] = acc[m][n][r] + bias[e];
            }
        }
    }
}

// ---------------- flash attention: KVBLK=64, swapped QK^T, in-register softmax ----
__global__ __launch_bounds__(512, 4) void attn256(const bf16* __restrict__ q,
                                                  const bf16* __restrict__ k,
                                                  const bf16* __restrict__ vT,
                                                  const int* __restrict__ mask,
                                                  bf16* __restrict__ o) {
    __shared__ bf16 lK[2][64 * 64];   // [k 64][c 64], row slots xor-swizzled by (k&7)
    __shared__ bf16 lV[2][64 * 64];   // [c 64][k 64], row slots xor-swizzled by (c&7)
    __shared__ float lMf[1024];       // mask -> {0, -1e38}

    const int tid = threadIdx.x;
    const int wv = tid >> 6, lane = tid & 63;
    const int q32 = lane & 31, hi = lane >> 5;

    const int wg = blockIdx.x;
    const int xcd = wg & 7, slot = wg >> 3;
    const int bh = xcd * 32 + (slot >> 1), qc = slot & 1;
    const int b = bh >> 3, h = bh & 7;

    const bf16* kbase = k + (long)bh * L_SZ * 64;
    const bf16* vbase = vT + (long)bh * 64 * L_SZ;

    const int* mrow = mask + b * L_SZ;
    lMf[tid] = mrow[tid] ? -1e38f : 0.f;
    lMf[tid + 512] = mrow[tid + 512] ? -1e38f : 0.f;

    const int r_ = tid >> 3, j_ = tid & 7;
    const int gj_ = (j_ ^ (r_ & 7)) * 8;
    const bf16* gK = kbase + r_ * 64 + gj_;           // +4096 per tile
    const bf16* gV = vbase + (long)r_ * L_SZ + gj_;   // +64 per tile
    char* dK0 = (char*)(&lK[0][0]) + tid * 16;
    char* dK1 = (char*)(&lK[1][0]) + tid * 16;
    char* dV0 = (char*)(&lV[0][0]) + tid * 16;
    char* dV1 = (char*)(&lV[1][0]) + tid * 16;
    gload16(dK0, gK);
    gload16(dV0, gV);

    const bf16* qp = q + ((long)bh * N_SZ + qc * 256 + wv * 32 + q32) * 64 + hi * 8;
    short8 qf[4];
#pragma unroll
    for (int t = 0; t < 4; ++t) qf[t] = *(const short8*)(qp + t * 16);

    float mrun = 0.f, lrun = 0.f;
    f32x16 oa0, oa1;
#pragma unroll
    for (int i = 0; i < 16; ++i) { oa0[i] = 0.f; oa1[i] = 0.f; }

    __syncthreads();

    const float CL = 0.18033688011112042f;  // SCALE * log2(e)

    for (int kb = 0; kb < 16; ++kb) {
        const char* curK = (const char*)(&lK[kb & 1][0]);
        const char* curV = (const char*)(&lV[kb & 1][0]);
        if (kb < 15) {
            gload16((kb & 1) ? dK0 : dK1, gK + (kb + 1) * 4096);
            gload16((kb & 1) ? dV0 : dV1, gV + (kb + 1) * 64);
        }

        // S^T: two independent chains (k rows 0-31 and 32-63)
        f32x16 sA, sB;
#pragma unroll
        for (int i = 0; i < 16; ++i) { sA[i] = 0.f; sB[i] = 0.f; }
#pragma unroll
        for (int t = 0; t < 4; ++t) {
            int sl = ((t * 2 + hi) ^ (q32 & 7)) * 16;
            short8 kfA = *(const short8*)(curK + q32 * 128 + sl);
            short8 kfB = *(const short8*)(curK + (32 + q32) * 128 + sl);
            sA = __builtin_amdgcn_mfma_f32_32x32x16_bf16(kfA, qf[t], sA, 0, 0, 0);
            sB = __builtin_amdgcn_mfma_f32_32x32x16_bf16(kfB, qf[t], sB, 0, 0, 0);
        }

        // mask bias: sA reg i -> k_local = (i&3) + 8*(i>>2) + 4*hi; sB: +32
        const float* mf = lMf + kb * 64 + hi * 4;
        float4 ma0 = *(const float4*)(mf);
        float4 ma1 = *(const float4*)(mf + 8);
        float4 ma2 = *(const float4*)(mf + 16);
        float4 ma3 = *(const float4*)(mf + 24);
        float4 mb0 = *(const float4*)(mf + 32);
        float4 mb1 = *(const float4*)(mf + 40);
        float4 mb2 = *(const float4*)(mf + 48);
        float4 mb3 = *(const float4*)(mf + 56);
        float mba[16] = {ma0.x, ma0.y, ma0.z, ma0.w, ma1.x, ma1.y, ma1.z, ma1.w,
                         ma2.x, ma2.y, ma2.z, ma2.w, ma3.x, ma3.y, ma3.z, ma3.w};
        float mbb[16] = {mb0.x, mb0.y, mb0.z, mb0.w, mb1.x, mb1.y, mb1.z, mb1.w,
                         mb2.x, mb2.y, mb2.z, mb2.w, mb3.x, mb3.y, mb3.z, mb3.w};

        float t32[32];
#pragma unroll
        for (int i = 0; i < 16; ++i) {
            t32[i] = fmaf(sA[i], CL, mba[i]);
            t32[16 + i] = fmaf(sB[i], CL, mbb[i]);
        }

        // tile max over 64 k
        float m16[16];
#pragma unroll
        for (int i = 0; i < 16; ++i) m16[i] = fmaxf(t32[i], t32[16 + i]);
        float m8[8];
#pragma unroll
        for (int i = 0; i < 8; ++i) m8[i] = fmaxf(m16[i], m16[i + 8]);
        float tm = fmaxf(fmaxf(fmaxf(m8[0], m8[4]), fmaxf(m8[1], m8[5])),
                         fmaxf(fmaxf(m8[2], m8[6]), fmaxf(m8[3], m8[7])));
        tm = fmaxf(tm, __shfl_xor(tm, 32));

        // defer-max (T13)
        if (__any(tm > mrun + 8.f)) {
            float mnew = fmaxf(mrun, tm);
            float al = fexp2(mrun - mnew);
            mrun = mnew;
            lrun *= al;
#pragma unroll
            for (int i = 0; i < 16; ++i) { oa0[i] *= al; oa1[i] *= al; }
        }

#pragma unroll
        for (int i = 0; i < 32; ++i) t32[i] = fexp2(t32[i] - mrun);
        float s16[16];
#pragma unroll
        for (int i = 0; i < 16; ++i) s16[i] = t32[i] + t32[16 + i];
        float s8[8];
#pragma unroll
        for (int i = 0; i < 8; ++i) s8[i] = s16[i] + s16[i + 8];
        float ps = ((s8[0] + s8[4]) + (s8[1] + s8[5])) + ((s8[2] + s8[6]) + (s8[3] + s8[7]));
        ps += __shfl_xor(ps, 32);
        lrun += ps;

        // P -> 4 bf16 B-fragments via cvt_pk + permlane32_swap
        union U { unsigned int u[4]; short8 s8v; };
        U fr[4];
#pragma unroll
        for (int fkt = 0; fkt < 4; ++fkt) {
            const float* tp = t32 + fkt * 8;
            unsigned int y0 = cvtpk(tp[0], tp[1]);
            unsigned int y1 = cvtpk(tp[2], tp[3]);
            unsigned int y2 = cvtpk(tp[4], tp[5]);
            unsigned int y3 = cvtpk(tp[6], tp[7]);
            asm("v_permlane32_swap_b32 %0, %1" : "+v"(y0), "+v"(y2));
            asm("v_permlane32_swap_b32 %0, %1" : "+v"(y1), "+v"(y3));
            fr[fkt].u[0] = y0; fr[fkt].u[1] = y1; fr[fkt].u[2] = y2; fr[fkt].u[3] = y3;
        }

        // O^T += V^T . P^T  (2 c-tiles x 4 k-quarters)
#pragma unroll
        for (int kt = 0; kt < 4; ++kt) {
            int sw = ((kt * 2 + hi) ^ (q32 & 7)) * 16;
            short8 v0 = *(const short8*)(curV + q32 * 128 + sw);
            short8 v1 = *(const short8*)(curV + (32 + q32) * 128 + sw);
            oa0 = __builtin_amdgcn_mfma_f32_32x32x16_bf16(v0, fr[kt].s8v, oa0, 0, 0, 0);
            oa1 = __builtin_amdgcn_mfma_f32_32x32x16_bf16(v1, fr[kt].s8v, oa1, 0, 0, 0);
        }

        __syncthreads();
    }

    // epilogue: O^T[c][q] -> o[b][q][h*64 + c]
    float inv = 1.f / lrun;
    bf16* op = o + ((long)b * N_SZ + qc * 256 + wv * 32 + q32) * 512 + h * 64;
#pragma unroll
    for (int ct = 0; ct < 2; ++ct) {
#pragma unroll
        for (int rq = 0; rq < 4; ++rq) {
            int c0 = ct * 32 + rq * 8 + hi * 4;
            float v0 = (ct ? oa1[rq * 4 + 0] : oa0[rq * 4 + 0]) * inv;
            float v1 = (ct ? oa1[rq * 4 + 1] : oa0[rq * 4 + 1]) * inv;
            float v2 = (ct ? oa1[rq * 4 + 2] : oa0[rq * 4 + 2]) * inv;
            float v3 = (ct ? oa1[rq * 4 + 3] : oa0[rq * 4 + 3]) * inv;
            uint2 st;
            st.x = cvtpk(v0, v1);
            st.y = cvtpk(v2, v3);
            *(uint2*)(op + c0) = st;
        }
    }
}

extern "C" void kernel_launch(void* const* d_in, const int* in_sizes, int n_in,
                              void* d_out, int out_size, void* d_ws, size_t ws_size,
                              hipStream_t stream) {
    const float* x_q  = (const float*)d_in[0];
    const float* x_kv = (const float*)d_in[1];
    const int*   mask = (const int*)d_in[2];
    const float* Wq   = (const float*)d_in[3];
    const float* Wk   = (const float*)d_in[4];
    const float* Wv   = (const float*)d_in[5];
    const float* Wo   = (const float*)d_in[6];
    const float* bo   = (const float*)d_in[7];
    const float* rpb  = (const float*)d_in[8];
    float* out = (float*)d_out;

    char* w = (char*)d_ws;
    bf16* xq_bf  = (bf16*)(w + 0);           // reused as o_bf after attention
    bf16* xkv_bf = (bf16*)(w + 16777216);
    bf16* WqT    = (bf16*)(w + 50331648);
    bf16* WkT    = WqT + 262144;
    bf16* WvT    = WkT + 262144;
    bf16* WoT    = WvT + 262144;
    bf16* qh     = (bf16*)(w + 52428800);    // [b][h][n][c]
    bf16* kh     = (bf16*)(w + 69206016);    // [b][h][l][c]
    bf16* vTh    = (bf16*)(w + 102760448);   // [b][h][c][l]
    bf16* o_bf   = xq_bf;

    cvt_all<<<24576, 256, 0, stream>>>(x_q, x_kv, xq_bf, xkv_bf);
    tpose4<<<dim3(16, 16, 4), dim3(32, 8), 0, stream>>>(Wq, Wk, Wv, Wo, WqT, WkT, WvT, WoT);

    gemm_qkv<<<2560, 256, 0, stream>>>(xq_bf, xkv_bf, WqT, WkT, WvT, rpb, qh, kh, vTh);

    attn256<<<512, 512, 0, stream>>>(qh, kh, vTh, mask, o_bf);

    gemm_o<<<512, 256, 0, stream>>>(o_bf, WoT, out, bo);
}